// Round 26
// baseline (366.772 us; speedup 1.0000x reference)
//
#include <hip/hip_runtime.h>

#define NWIN 128       // B * nW windows
#define NTOK 392       // tokens per window (8*7*7)
#define SPAT 25088     // D*H*W
#define NELEM 4816896  // 2*96*25088

typedef unsigned short u16t;
typedef unsigned int u32t;
typedef __attribute__((ext_vector_type(8))) short short8;
typedef __attribute__((ext_vector_type(4))) float f32x4;

// xpad geometry: CHANNEL-LAST [b][10][58][58][96] bf16, zero border
#define PW 58
#define PHW 3364      // 58*58
#define PSPAT 33640   // 10*58*58
#define XPAD_U16 6458880   // 2*33640*96
#define WCOMB_N 248832     // 27*96*96
#define WPROJ_N 18432      // 96*192
#define NTOKTOT 50176      // NWIN*NTOK
#define LOG2E 1.44269504f

// ---------- helpers ----------
__device__ __forceinline__ unsigned int f2bf(float f) {
  unsigned int u = __float_as_uint(f);
  return (u + 0x7fffu + ((u >> 16) & 1u)) >> 16;   // RNE to bf16
}
__device__ __forceinline__ unsigned int pack2(float a, float b) {
  return f2bf(a) | (f2bf(b) << 16);
}
__device__ __forceinline__ u32t cvtpk(float lo, float hi) {
  u32t r;
  asm("v_cvt_pk_bf16_f32 %0, %1, %2" : "=v"(r) : "v"(lo), "v"(hi));
  return r;
}
__device__ __forceinline__ float exp2v(float x) {
  return __builtin_amdgcn_exp2f(x);   // raw v_exp_f32 (2^x)
}
__device__ __forceinline__ float bflo(unsigned int u) { return __uint_as_float(u << 16); }

// ---------- kernel 1: LN1 over C + roll(-4,-3,-3) + window partition (bf16 out) ----------
__global__ __launch_bounds__(256)
void k_ln1_win(const float* __restrict__ x, const float* __restrict__ lw,
               const float* __restrict__ lb, u16t* __restrict__ xw) {
  int p = blockIdx.x * 256 + threadIdx.x;       // 0..50175
  int b = p / SPAT, s = p % SPAT;
  int d = s / 3136, r = s % 3136, h = r / 56, w = r % 56;
  const float* xp = x + (size_t)b * 96 * SPAT + s;
  float sum = 0.f, sq = 0.f;
  #pragma unroll 8
  for (int c = 0; c < 96; ++c) {
    float v = xp[(size_t)c * SPAT];
    sum += v; sq += v * v;
  }
  float mu = sum * (1.f / 96.f);
  float var = sq * (1.f / 96.f) - mu * mu;
  float rs = rsqrtf(var + 1e-5f);
  int ds = (d + 4) & 7;                          // (d-4) mod 8
  int hs = h - 3; if (hs < 0) hs += 56;
  int ws = w - 3; if (ws < 0) ws += 56;
  int win = b * 64 + (hs / 7) * 8 + (ws / 7);
  int n = ds * 49 + (hs % 7) * 7 + (ws % 7);
  u16t* op = xw + (size_t)(win * NTOK + n) * 96;
  #pragma unroll
  for (int g = 0; g < 12; ++g) {
    float v0 = xp[(size_t)(8 * g + 0) * SPAT], v1 = xp[(size_t)(8 * g + 1) * SPAT];
    float v2 = xp[(size_t)(8 * g + 2) * SPAT], v3 = xp[(size_t)(8 * g + 3) * SPAT];
    float v4 = xp[(size_t)(8 * g + 4) * SPAT], v5 = xp[(size_t)(8 * g + 5) * SPAT];
    float v6 = xp[(size_t)(8 * g + 6) * SPAT], v7 = xp[(size_t)(8 * g + 7) * SPAT];
    uint4 st;
    st.x = pack2((v0 - mu) * rs * lw[8*g+0] + lb[8*g+0], (v1 - mu) * rs * lw[8*g+1] + lb[8*g+1]);
    st.y = pack2((v2 - mu) * rs * lw[8*g+2] + lb[8*g+2], (v3 - mu) * rs * lw[8*g+3] + lb[8*g+3]);
    st.z = pack2((v4 - mu) * rs * lw[8*g+4] + lb[8*g+4], (v5 - mu) * rs * lw[8*g+5] + lb[8*g+5]);
    st.w = pack2((v6 - mu) * rs * lw[8*g+6] + lb[8*g+6], (v7 - mu) * rs * lw[8*g+7] + lb[8*g+7]);
    *reinterpret_cast<uint4*>(op + g * 8) = st;
  }
}

// ---------- kernel 2a: qkv weights -> bf16 (both heads) ----------
__global__ __launch_bounds__(256)
void k_qprep(const float* __restrict__ w0, const float* __restrict__ w1,
             u16t* __restrict__ wq) {
  int e = blockIdx.x * 256 + threadIdx.x;
  if (e >= 2 * 27648) return;
  wq[e] = (u16t)f2bf(e < 27648 ? w0[e] : w1[e - 27648]);
}

// ---------- kernel 2b: qkv GEMM via MFMA -> head-major dense [sel][head][tok][dh] ----------
template<int DH>
__global__ __launch_bounds__(256)
void k_qkv_mfma(const u16t* __restrict__ xw, const u16t* __restrict__ wq,
                const float* __restrict__ bias, u16t* __restrict__ qkvh) {
  int tid = threadIdx.x;
  int lane = tid & 63, wv = tid >> 6;
  int c = lane & 15, lg = lane >> 4;
  int t = blockIdx.x * 64 + wv * 16 + c;
  const u16t* bp = xw + (size_t)t * 96 + lg * 8;
  short8 bv[3];
  #pragma unroll
  for (int kc = 0; kc < 3; ++kc)
    bv[kc] = *reinterpret_cast<const short8*>(bp + kc * 32);
  f32x4 acc[18];
  #pragma unroll
  for (int f = 0; f < 18; ++f) acc[f] = (f32x4){0.f, 0.f, 0.f, 0.f};
  #pragma unroll
  for (int kc = 0; kc < 3; ++kc) {
    #pragma unroll
    for (int f = 0; f < 18; ++f) {
      short8 av = *reinterpret_cast<const short8*>(
          wq + (size_t)(f * 16 + c) * 96 + kc * 32 + lg * 8);
      acc[f] = __builtin_amdgcn_mfma_f32_16x16x32_bf16(av, bv[kc], acc[f], 0, 0, 0);
    }
  }
  #pragma unroll
  for (int f = 0; f < 18; ++f) {
    int co = f * 16 + lg * 4;
    float4 bb = *reinterpret_cast<const float4*>(bias + co);
    uint2 st = make_uint2(pack2(acc[f][0] + bb.x, acc[f][1] + bb.y),
                          pack2(acc[f][2] + bb.z, acc[f][3] + bb.w));
    int sel = co / 96, rem = co % 96;
    int head = rem / DH, dh = rem % DH;
    *reinterpret_cast<uint2*>(qkvh + (size_t)sel * NTOKTOT * 96
        + (size_t)head * NTOKTOT * DH + (size_t)t * DH + dh) = st;
  }
}

// ---------- kernel 2c: rpb -> per-head-contiguous bf16 [h][2536], pre-scaled by log2e ----------
template<int H>
__global__ __launch_bounds__(256)
void k_rprep(const float* __restrict__ rpb, u16t* __restrict__ rpbc) {
  int e = blockIdx.x * 256 + threadIdx.x;
  if (e >= H * 2536) return;
  int h = e / 2536, idx = e % 2536;
  rpbc[e] = (idx < 2535) ? (u16t)f2bf(rpb[idx * H + h] * LOG2E) : (u16t)0;
}

// ---------- kernel 3: MFMA window attention, online softmax (log2 domain), 8 waves ----------
// Region-disjoint tile PRE-skip (wave-uniform, before MFMA) + data-dependent post-skip.
template<int H, int DH>
__global__ __launch_bounds__(512, (DH == 16) ? 6 : 4)
void k_attn_mfma(const u16t* __restrict__ qkvh, const u16t* __restrict__ rpbc,
                 u16t* __restrict__ aout) {
  constexpr float SCALE2 = ((DH == 32) ? 0.17677669529663689f : 0.25f) * LOG2E;
  constexpr float MASKV = -100.f * LOG2E;
  constexpr float THR = 8.f * LOG2E;
  constexpr int NT = DH / 16;
  constexpr int QSPLIT = (DH == 16) ? 1 : 2;
  constexpr int KROW = (DH == 32) ? 32 : 16;
  constexpr int KS_U16 = (DH == 32) ? (416 * 32) : (417 * 16);  // DH16: extra zero row
  constexpr int BLK = 512;
  __shared__ __align__(16) u16t Ks[KS_U16];
  __shared__ __align__(16) u16t VTs[DH * 424];    // [dh][tok], stride 424
  __shared__ u16t rpbs[2536];                      // compact per-head bias (log2-scaled)
  __shared__ u16t Ts[416];                         // token coord codes (0 for pads)
  __shared__ u32t RGp[104];                        // packed region ids (255 for pads)
  __shared__ u32t RGm[26];                         // per-16-token-group region bitmask

  int bid = blockIdx.x;
  int xcd = bid & 7, i = bid >> 3;
  int win = xcd * 16 + (i & 15);
  int hp = i >> 4;
  int head = (DH == 32) ? (hp >> 1) : hp;
  int part = (DH == 32) ? (hp & 1) : 0;
  int wrem = win & 63;
  int hwin = wrem >> 3, wwin = wrem & 7;
  int tid = threadIdx.x;
  int lane = tid & 63, wv = tid >> 6;
  int c = lane & 15, lg = lane >> 4;

  const u16t* qh = qkvh + (size_t)head * NTOKTOT * DH + (size_t)win * NTOK * DH;
  const u16t* kh = qh + (size_t)NTOKTOT * 96;
  const u16t* vh = qh + (size_t)2 * NTOKTOT * 96;
  u16t* ao = aout + (size_t)head * NTOKTOT * DH + (size_t)win * NTOK * DH;

  {  // zero K/V (pads must be 0)
    uint4 z = make_uint4(0u, 0u, 0u, 0u);
    uint4* k4 = (uint4*)Ks;
    for (int i2 = tid; i2 < KS_U16 / 8; i2 += BLK) k4[i2] = z;
    uint4* v4 = (uint4*)VTs;
    for (int i2 = tid; i2 < (DH * 424) / 8; i2 += BLK) v4[i2] = z;
  }
  __syncthreads();
  constexpr int DG = DH / 8;
  for (int u = tid; u < NTOK * DG; u += BLK) {
    int j = u / DG, dg = u % DG;
    uint4 kv = *reinterpret_cast<const uint4*>(kh + (size_t)j * DH + dg * 8);
    int sch = (DH == 32) ? (dg ^ (j & 3)) : (dg ^ ((j & 1) ^ ((j >> 2) & 1)));
    *reinterpret_cast<uint4*>(&Ks[j * KROW + sch * 8]) = kv;
    union { uint4 q; u16t s[8]; } vv;
    vv.q = *reinterpret_cast<const uint4*>(vh + (size_t)j * DH + dg * 8);
    #pragma unroll
    for (int ee = 0; ee < 8; ++ee) VTs[(dg * 8 + ee) * 424 + j] = vv.s[ee];
  }
  for (int i2 = tid; i2 < 2536; i2 += BLK) rpbs[i2] = rpbc[head * 2536 + i2];
  for (int j = tid; j < 416; j += BLK) {
    u16t tv = 0;
    if (j < NTOK) {
      int ld = j / 49, r = j % 49, lh = r / 7, lw = r % 7;
      tv = (u16t)(ld * 169 + lh * 13 + lw);
    }
    Ts[j] = tv;
  }
  for (int j4 = tid; j4 < 104; j4 += BLK) {
    u32t w = 0;
    #pragma unroll
    for (int bb = 0; bb < 4; ++bb) {
      int j = j4 * 4 + bb;
      u32t rg = 255;
      if (j < NTOK) {
        int ld = j / 49, r = j % 49, lh = r / 7, lw = r % 7;
        int hpp = hwin * 7 + lh, wpp = wwin * 7 + lw;
        int rd = (ld < 4) ? 1 : 2;
        int rh = (hpp < 49) ? 0 : ((hpp < 53) ? 1 : 2);
        int rw = (wpp < 49) ? 0 : ((wpp < 53) ? 1 : 2);
        rg = (u32t)(rd * 9 + rh * 3 + rw);
      }
      w |= rg << (8 * bb);
    }
    RGp[j4] = w;
  }
  __syncthreads();
  if (tid < 26) {          // group region bitmask (27 region ids; pads add no bits)
    u32t msk = 0;
    #pragma unroll
    for (int j4 = 0; j4 < 4; ++j4) {
      u32t w = RGp[tid * 4 + j4];
      #pragma unroll
      for (int bb = 0; bb < 4; ++bb) {
        u32t rg = (w >> (8 * bb)) & 255u;
        if (rg < 27u) msk |= (1u << rg);
      }
    }
    RGm[tid] = msk;
  }
  __syncthreads();

  constexpr int QBASE = 25 / QSPLIT;
  constexpr int QREM = 25 % QSPLIT;
  int q0 = part * QBASE + ((part < QREM) ? part : QREM);
  int q1 = q0 + QBASE + ((part < QREM) ? 1 : 0);

  for (int qt = q0 + wv; qt < q1; qt += 8) {
    int qtok = qt * 16 + c;
    int qcl = (qtok < NTOK) ? qtok : NTOK - 1;
    int Tq = (int)Ts[qcl] + 1267;
    u32t rgq = (RGp[qcl >> 2] >> ((qcl & 3) * 8)) & 255u;
    u32t qmask = RGm[qt < 25 ? qt : 24];
    short8 bq;
    {
      const u16t* qp = qh + (size_t)qcl * DH;
      union { u32t u[4]; short8 v; } bu;
      #pragma unroll
      for (int i2 = 0; i2 < 4; ++i2) {
        u16t e0 = (DH == 32 || lg < 2) ? qp[lg * 8 + 2 * i2] : (u16t)0;
        u16t e1 = (DH == 32 || lg < 2) ? qp[lg * 8 + 2 * i2 + 1] : (u16t)0;
        bu.u[i2] = (u32t)e0 | ((u32t)e1 << 16);
      }
      bq = bu.v;
    }
    float m = -1e30f, lsum = 0.f;
    f32x4 oacc[NT];
    #pragma unroll
    for (int ot = 0; ot < NT; ++ot) oacc[ot] = (f32x4){0.f, 0.f, 0.f, 0.f};
    int srcl = ((lane >> 4) & 1) * 32 + c;
    #pragma unroll 1
    for (int tt = 0; tt < 13; ++tt) {
      // region-disjoint PRE-skip (wave-uniform): whole 16q x 32k tile masked
      u32t kmask = RGm[2 * tt] | ((2 * tt + 1 < 26) ? RGm[2 * tt + 1] : 0u);
      if ((qmask & kmask) == 0u) continue;
      f32x4 p0, p1;
      #pragma unroll
      for (int half = 0; half < 2; ++half) {
        int t = 2 * tt + half;
        int addr;
        if (DH == 32) {
          addr = (16 * t + c) * 32 + ((lg ^ (c & 3)) * 8);
        } else {
          int fc = (c & 1) ^ ((c >> 2) & 1);
          addr = (lg < 2) ? ((16 * t + c) * 16 + (((lg & 1) ^ fc) * 8)) : (416 * 16);
        }
        short8 av = *reinterpret_cast<const short8*>(&Ks[addr]);
        f32x4 a = (f32x4){0.f, 0.f, 0.f, 0.f};
        a = __builtin_amdgcn_mfma_f32_16x16x32_bf16(av, bq, a, 0, 0, 0);
        int kb = 16 * t + lg * 4;
        const u32t* tsp = reinterpret_cast<const u32t*>(&Ts[kb]);
        u32t tsa = tsp[0], tsb = tsp[1];
        u32t rgw = RGp[4 * t + lg];
        f32x4 p;
        p[0] = a[0] * SCALE2 + bflo((u32t)rpbs[Tq - (int)(tsa & 0xffffu)])
             + ((((rgw      ) & 255u) != rgq) ? MASKV : 0.f);
        p[1] = a[1] * SCALE2 + bflo((u32t)rpbs[Tq - (int)(tsa >> 16)])
             + ((((rgw >>  8) & 255u) != rgq) ? MASKV : 0.f);
        p[2] = a[2] * SCALE2 + bflo((u32t)rpbs[Tq - (int)(tsb & 0xffffu)])
             + ((((rgw >> 16) & 255u) != rgq) ? MASKV : 0.f);
        p[3] = a[3] * SCALE2 + bflo((u32t)rpbs[Tq - (int)(tsb >> 16)])
             + ((((rgw >> 24)        ) != rgq) ? MASKV : 0.f);
        if (half == 0) p0 = p; else p1 = p;
      }
      float pm = fmaxf(fmaxf(fmaxf(p0[0], p0[1]), fmaxf(p0[2], p0[3])),
                       fmaxf(fmaxf(p1[0], p1[1]), fmaxf(p1[2], p1[3])));
      pm = fmaxf(pm, __shfl_xor(pm, 16));
      pm = fmaxf(pm, __shfl_xor(pm, 32));
      bool dead = (pm <= m - 25.f) || (pm <= -90.f);
      if (__all(dead)) continue;
      if (!__all(pm <= m + THR)) {           // rescale only when some lane's max grew
        float mnew = fmaxf(pm, m);           // per-lane
        float fac = exp2v(m - mnew);
        lsum *= fac;
        #pragma unroll
        for (int ot = 0; ot < NT; ++ot) oacc[ot] *= fac;
        m = mnew;
      }
      #pragma unroll
      for (int j = 0; j < 4; ++j) {
        p0[j] = exp2v(p0[j] - m);
        p1[j] = exp2v(p1[j] - m);
      }
      lsum += p0[0] + p0[1] + p0[2] + p0[3] + p1[0] + p1[1] + p1[2] + p1[3];
      u32t pk0x = cvtpk(p0[0], p0[1]);
      u32t pk0y = cvtpk(p0[2], p0[3]);
      u32t pk1x = cvtpk(p1[0], p1[1]);
      u32t pk1y = cvtpk(p1[2], p1[3]);
      u32t ax = (u32t)__shfl((int)pk0x, srcl),      ay = (u32t)__shfl((int)pk0y, srcl);
      u32t bx = (u32t)__shfl((int)pk0x, srcl + 16), by = (u32t)__shfl((int)pk0y, srcl + 16);
      u32t cx = (u32t)__shfl((int)pk1x, srcl),      cy = (u32t)__shfl((int)pk1y, srcl);
      u32t dx = (u32t)__shfl((int)pk1x, srcl + 16), dy = (u32t)__shfl((int)pk1y, srcl + 16);
      bool hi = (lane & 32) != 0;
      union { u32t u[4]; short8 v; } au;
      au.u[0] = hi ? cx : ax; au.u[1] = hi ? cy : ay;
      au.u[2] = hi ? dx : bx; au.u[3] = hi ? dy : by;
      #pragma unroll
      for (int ot = 0; ot < NT; ++ot) {
        short8 bv = *reinterpret_cast<const short8*>(
            &VTs[(ot * 16 + c) * 424 + 32 * tt + lg * 8]);
        oacc[ot] = __builtin_amdgcn_mfma_f32_16x16x32_bf16(au.v, bv, oacc[ot], 0, 0, 0);
      }
    }
    lsum += __shfl_xor(lsum, 16);
    lsum += __shfl_xor(lsum, 32);
    float inv = 1.f / lsum;
    float invj[4];
    #pragma unroll
    for (int j = 0; j < 4; ++j) invj[j] = __shfl(inv, lg * 4 + j);
    #pragma unroll
    for (int j = 0; j < 4; ++j) {
      int q = qt * 16 + lg * 4 + j;
      if (q < NTOK) {
        #pragma unroll
        for (int ot = 0; ot < NT; ++ot)
          ao[(size_t)q * DH + ot * 16 + c] = (u16t)f2bf(oacc[ot][j] * invj[j]);
      }
    }
  }
}

// ---------- kernel 4a: combined proj weights (alpha folded), bf16 ----------
__global__ __launch_bounds__(256)
void k_pprep(const float* __restrict__ pw0, const float* __restrict__ pb0,
             const float* __restrict__ pw1, const float* __restrict__ pb1,
             const float* __restrict__ alpha,
             u16t* __restrict__ wp, float* __restrict__ bp) {
  int e = blockIdx.x * 256 + threadIdx.x;
  if (e >= WPROJ_N) return;
  float al0 = alpha[0], al1 = alpha[1];
  float m = fmaxf(al0, al1);
  float e0 = expf(al0 - m), e1 = expf(al1 - m);
  float aw0 = e0 / (e0 + e1), aw1 = e1 / (e0 + e1);
  int co = e / 192, k = e % 192;
  float v = (k < 96) ? aw0 * pw0[co * 96 + k] : aw1 * pw1[co * 96 + k - 96];
  wp[e] = (u16t)f2bf(v);
  if (e < 96) bp[e] = aw0 * pb0[e] + aw1 * pb1[e];
}

// ---------- kernel 4b: proj via MFMA + window reverse + unshift + residual ----------
__global__ __launch_bounds__(64)
void k_proj_mfma(const u16t* __restrict__ a0, const u16t* __restrict__ a1,
                 const u16t* __restrict__ wp, const float* __restrict__ bp,
                 const float* __restrict__ x, float* __restrict__ x1) {
  int lane = threadIdx.x;
  int c = lane & 15, lg = lane >> 4;
  int t = blockIdx.x * 16 + c;
  int win = t / NTOK, n = t % NTOK;
  int b = win >> 6, wrem = win & 63;
  int hwin = wrem >> 3, wwin = wrem & 7;
  int ld = n / 49, r = n % 49, lh = r / 7, lw = r % 7;
  int d = (ld + 4) & 7;
  int h = (hwin * 7 + lh + 3) % 56;
  int w = (wwin * 7 + lw + 3) % 56;
  size_t base = (size_t)b * 96 * SPAT + d * 3136 + h * 56 + w;

  f32x4 acc[6];
  #pragma unroll
  for (int f = 0; f < 6; ++f) acc[f] = (f32x4){0.f, 0.f, 0.f, 0.f};
  #pragma unroll
  for (int kc = 0; kc < 6; ++kc) {
    short8 bv;
    if (kc < 3) {
      bv = *reinterpret_cast<const short8*>(a0 + ((size_t)kc * NTOKTOT + t) * 32 + lg * 8);
    } else {
      int h1 = (kc - 3) * 2 + (lg >> 1);
      bv = *reinterpret_cast<const short8*>(a1 + ((size_t)h1 * NTOKTOT + t) * 16 + (lg & 1) * 8);
    }
    #pragma unroll
    for (int f = 0; f < 6; ++f) {
      short8 av = *reinterpret_cast<const short8*>(wp + (f * 16 + c) * 192 + kc * 32 + lg * 8);
      acc[f] = __builtin_amdgcn_mfma_f32_16x16x32_bf16(av, bv, acc[f], 0, 0, 0);
    }
  }
  #pragma unroll
  for (int f = 0; f < 6; ++f) {
    #pragma unroll
    for (int j = 0; j < 4; ++j) {
      int co = f * 16 + lg * 4 + j;
      size_t idx = base + (size_t)co * SPAT;
      x1[idx] = x[idx] + acc[f][j] + bp[co];
    }
  }
}

// ---------- kernel 5a: zero xpad ----------
__global__ __launch_bounds__(256)
void k_zero(uint4* __restrict__ p, int n) {
  int i = blockIdx.x * 256 + threadIdx.x;
  if (i < n) p[i] = make_uint4(0u, 0u, 0u, 0u);
}

// ---------- kernel 5b: combined FFN weights (softmax-alpha folded), bf16 ----------
__global__ __launch_bounds__(256)
void k_wprep(const float* __restrict__ c3w, const float* __restrict__ c3b,
             const float* __restrict__ c1w, const float* __restrict__ c1b,
             const float* __restrict__ dww, const float* __restrict__ dwb,
             const float* __restrict__ alpha,
             u16t* __restrict__ wcomb, float* __restrict__ bcomb) {
  int e = blockIdx.x * 256 + threadIdx.x;
  if (e >= WCOMB_N) return;
  float a0 = alpha[0], a1 = alpha[1], a2 = alpha[2], a3 = alpha[3];
  float mx = fmaxf(fmaxf(a0, a1), fmaxf(a2, a3));
  float e0 = expf(a0 - mx), e1 = expf(a1 - mx), e2 = expf(a2 - mx), e3 = expf(a3 - mx);
  float inv = 1.f / (e0 + e1 + e2 + e3);
  float f0 = e0 * inv, f1 = e1 * inv, f2 = e2 * inv, f3 = e3 * inv;
  int ko = e / 9216, rm = e % 9216, co = rm / 96, ci = rm % 96;
  float v = f0 * c3w[(co * 96 + ci) * 27 + ko];
  if (ko == 13) v += f1 * c1w[co * 96 + ci];
  if (ci == co) v += f2 * dww[co * 27 + ko];
  if (ko == 13 && ci == co) v += f3;
  wcomb[e] = (u16t)f2bf(v);
  if (e < 96) bcomb[e] = f0 * c3b[e] + f1 * c1b[e] + f2 * dwb[e];
}

// ---------- kernel 5c: LN2 -> padded CHANNEL-LAST bf16 tensor ----------
__global__ __launch_bounds__(256)
void k_ln2pad(const float* __restrict__ x1, const float* __restrict__ lw,
              const float* __restrict__ lb, u16t* __restrict__ xpad) {
  int p = blockIdx.x * 256 + threadIdx.x;       // 0..50175
  int b = p / SPAT, s = p % SPAT;
  int d = s / 3136, r = s % 3136, h = r / 56, w = r % 56;
  const float* xp = x1 + (size_t)b * 96 * SPAT + s;
  float sum = 0.f, sq = 0.f;
  #pragma unroll 8
  for (int c = 0; c < 96; ++c) {
    float v = xp[(size_t)c * SPAT];
    sum += v; sq += v * v;
  }
  float mu = sum * (1.f / 96.f);
  float var = sq * (1.f / 96.f) - mu * mu;
  float rs = rsqrtf(var + 1e-5f);
  int psp = ((b * 10 + d + 1) * 58 + (h + 1)) * 58 + (w + 1);
  u16t* op = xpad + (size_t)psp * 96;
  #pragma unroll
  for (int g = 0; g < 12; ++g) {
    float v0 = xp[(size_t)(8 * g + 0) * SPAT], v1 = xp[(size_t)(8 * g + 1) * SPAT];
    float v2 = xp[(size_t)(8 * g + 2) * SPAT], v3 = xp[(size_t)(8 * g + 3) * SPAT];
    float v4 = xp[(size_t)(8 * g + 4) * SPAT], v5 = xp[(size_t)(8 * g + 5) * SPAT];
    float v6 = xp[(size_t)(8 * g + 6) * SPAT], v7 = xp[(size_t)(8 * g + 7) * SPAT];
    uint4 st;
    st.x = pack2((v0 - mu) * rs * lw[8*g+0] + lb[8*g+0], (v1 - mu) * rs * lw[8*g+1] + lb[8*g+1]);
    st.y = pack2((v2 - mu) * rs * lw[8*g+2] + lb[8*g+2], (v3 - mu) * rs * lw[8*g+3] + lb[8*g+3]);
    st.z = pack2((v4 - mu) * rs * lw[8*g+4] + lb[8*g+4], (v5 - mu) * rs * lw[8*g+5] + lb[8*g+5]);
    st.w = pack2((v6 - mu) * rs * lw[8*g+6] + lb[8*g+6], (v7 - mu) * rs * lw[8*g+7] + lb[8*g+7]);
    *reinterpret_cast<uint4*>(op + g * 8) = st;
  }
}

// ---------- kernel 6: FFN implicit GEMM via MFMA (channel-last xpad) ----------
// NO-LDS variant: A-frags read directly from L2/L1-resident wcomb (contiguous
// 16B per lane; 8 waves/block share identical A addresses -> L1 hits).
// 784 blocks = 2 co-halves x 392 sp-tiles; 8 waves x 512 thr; zero barriers.
__global__ __launch_bounds__(512)
void k_ffn_mfma(const u16t* __restrict__ xpad, const u16t* __restrict__ wcomb,
                const float* __restrict__ bcomb, float* __restrict__ out) {
  int tid = threadIdx.x;
  int lane = tid & 63, wv = tid >> 6;        // wv 0..7
  int c = lane & 15, kg = lane >> 4;
  int bid = blockIdx.x;
  int coh = bid & 1;                         // co half
  int sp = bid >> 1;                         // spatial tile 0..391
  int swz = (sp & 7) * 49 + (sp >> 3);       // bijective: 392 = 8*49
  int m = swz * 128 + wv * 16 + c;
  int b = m / SPAT, r = m % SPAT;
  int d = r / 3136, r2 = r % 3136, h = r2 / 56, w = r2 % 56;
  int psp0 = ((b * 10 + d) * 58 + h) * 58 + w;
  int pbase = psp0 * 96 + kg * 8;
  int obase = b * (96 * SPAT) + r;
  const u16t* wbase = wcomb + (coh * 48 + c) * 96 + kg * 8;   // row c, k-offset kg*8

  f32x4 acc[3];
  #pragma unroll
  for (int ff = 0; ff < 3; ++ff) acc[ff] = (f32x4){0.f, 0.f, 0.f, 0.f};

  #pragma unroll 1
  for (int ko = 0; ko < 27; ++ko) {
    int kd = ko / 9, kh = (ko / 3) % 3, kw = ko % 3;
    int tapoff = (kd * PHW + kh * PW + kw) * 96;
    const u16t* wko = wbase + ko * 9216;
    #pragma unroll
    for (int cc = 0; cc < 3; ++cc) {
      short8 bv = *reinterpret_cast<const short8*>(xpad + pbase + tapoff + cc * 32);
      #pragma unroll
      for (int ff = 0; ff < 3; ++ff) {
        short8 av = *reinterpret_cast<const short8*>(wko + ff * 16 * 96 + cc * 32);
        acc[ff] = __builtin_amdgcn_mfma_f32_16x16x32_bf16(av, bv, acc[ff], 0, 0, 0);
      }
    }
  }
  #pragma unroll
  for (int ff = 0; ff < 3; ++ff)
    #pragma unroll
    for (int j = 0; j < 4; ++j) {
      int co = coh * 48 + ff * 16 + kg * 4 + j;
      float* o = out + obase + co * SPAT;
      *o = *o + acc[ff][j] + bcomb[co];
    }
}

extern "C" void kernel_launch(void* const* d_in, const int* in_sizes, int n_in,
                              void* d_out, int out_size, void* d_ws, size_t ws_size,
                              hipStream_t stream) {
  (void)in_sizes; (void)n_in; (void)out_size; (void)ws_size;
  const float* x      = (const float*)d_in[0];
  const float* ln1w   = (const float*)d_in[1];
  const float* ln1b   = (const float*)d_in[2];
  const float* ln2w   = (const float*)d_in[3];
  const float* ln2b   = (const float*)d_in[4];
  const float* qkvw0  = (const float*)d_in[5];
  const float* qkvb0  = (const float*)d_in[6];
  const float* projw0 = (const float*)d_in[7];
  const float* projb0 = (const float*)d_in[8];
  const float* rpb0   = (const float*)d_in[9];
  const float* qkvw1  = (const float*)d_in[10];
  const float* qkvb1  = (const float*)d_in[11];
  const float* projw1 = (const float*)d_in[12];
  const float* projb1 = (const float*)d_in[13];
  const float* rpb1   = (const float*)d_in[14];
  const float* aattn  = (const float*)d_in[15];
  const float* c3w    = (const float*)d_in[16];
  const float* c3b    = (const float*)d_in[17];
  const float* c1w    = (const float*)d_in[18];
  const float* c1b    = (const float*)d_in[19];
  const float* dww    = (const float*)d_in[20];
  const float* dwb    = (const float*)d_in[21];
  const float* affn   = (const float*)d_in[22];

  // workspace (u16 units)
  u16t* u    = (u16t*)d_ws;
  u16t* xw   = u;                                  // 50176*96
  u16t* a0   = xw + (size_t)NTOKTOT * 96;          // 3*50176*32
  u16t* a1   = a0 + (size_t)3 * NTOKTOT * 32;      // 6*50176*16
  u16t* qkvh = a1 + (size_t)6 * NTOKTOT * 16;      // 3*50176*96 (q|k|v head-major)
  u16t* wq   = qkvh + (size_t)3 * NTOKTOT * 96;    // 2*27648
  u16t* rpbc0 = wq + 2 * 27648;                    // 3*2536
  u16t* rpbc1 = rpbc0 + 3 * 2536;                  // 6*2536
  u16t* xpad  = qkvh;                              // reuse (dead after attn), channel-last
  u16t* wcomb = xpad + XPAD_U16;
  float* bcomb = (float*)(wcomb + WCOMB_N);
  u16t* wproj = (u16t*)(bcomb + 96);
  float* bproj = (float*)(wproj + WPROJ_N);
  float* x1  = (float*)d_out;

  k_ln1_win<<<196, 256, 0, stream>>>(x, ln1w, ln1b, xw);
  k_qprep<<<216, 256, 0, stream>>>(qkvw0, qkvw1, wq);
  k_rprep<3><<<30, 256, 0, stream>>>(rpb0, rpbc0);
  k_rprep<6><<<60, 256, 0, stream>>>(rpb1, rpbc1);
  k_qkv_mfma<32><<<784, 256, 0, stream>>>(xw, wq, qkvb0, qkvh);
  k_attn_mfma<3, 32><<<768, 512, 0, stream>>>(qkvh, rpbc0, a0);
  k_qkv_mfma<16><<<784, 256, 0, stream>>>(xw, wq + 27648, qkvb1, qkvh);
  k_attn_mfma<6, 16><<<768, 512, 0, stream>>>(qkvh, rpbc1, a1);
  // qkvh dead: build xpad / combined weights in its place
  k_zero<<<(XPAD_U16 / 8 + 255) / 256, 256, 0, stream>>>((uint4*)xpad, XPAD_U16 / 8);
  k_wprep<<<(WCOMB_N + 255) / 256, 256, 0, stream>>>(c3w, c3b, c1w, c1b, dww, dwb,
                                                     affn, wcomb, bcomb);
  k_pprep<<<(WPROJ_N + 255) / 256, 256, 0, stream>>>(projw0, projb0, projw1, projb1,
                                                     aattn, wproj, bproj);
  k_proj_mfma<<<3136, 64, 0, stream>>>(a0, a1, wproj, bproj, x, x1);
  k_ln2pad<<<196, 256, 0, stream>>>(x1, ln2w, ln2b, xpad);
  k_ffn_mfma<<<784, 512, 0, stream>>>(xpad, wcomb, bcomb, (float*)d_out);
}

// Round 27
// 270.025 us; speedup vs baseline: 1.3583x; 1.3583x over previous
//
#include <hip/hip_runtime.h>

#define NWIN 128       // B * nW windows
#define NTOK 392       // tokens per window (8*7*7)
#define SPAT 25088     // D*H*W
#define NELEM 4816896  // 2*96*25088

typedef unsigned short u16t;
typedef unsigned int u32t;
typedef __attribute__((ext_vector_type(8))) short short8;
typedef __attribute__((ext_vector_type(4))) float f32x4;

// xpad geometry: CHANNEL-LAST [b][10][58][58][96] bf16, zero border
#define PW 58
#define PHW 3364      // 58*58
#define PSPAT 33640   // 10*58*58
#define XPAD_U16 6458880   // 2*33640*96
#define WCOMB_N 248832     // 27*96*96
#define WPROJ_N 18432      // 96*192
#define NTOKTOT 50176      // NWIN*NTOK
#define LOG2E 1.44269504f

// ---------- helpers ----------
__device__ __forceinline__ unsigned int f2bf(float f) {
  unsigned int u = __float_as_uint(f);
  return (u + 0x7fffu + ((u >> 16) & 1u)) >> 16;   // RNE to bf16
}
__device__ __forceinline__ unsigned int pack2(float a, float b) {
  return f2bf(a) | (f2bf(b) << 16);
}
__device__ __forceinline__ u32t cvtpk(float lo, float hi) {
  u32t r;
  asm("v_cvt_pk_bf16_f32 %0, %1, %2" : "=v"(r) : "v"(lo), "v"(hi));
  return r;
}
__device__ __forceinline__ float exp2v(float x) {
  return __builtin_amdgcn_exp2f(x);   // raw v_exp_f32 (2^x)
}
__device__ __forceinline__ float bflo(unsigned int u) { return __uint_as_float(u << 16); }

// ---------- kernel 1: LN1 over C + roll(-4,-3,-3) + window partition (bf16 out) ----------
__global__ __launch_bounds__(256)
void k_ln1_win(const float* __restrict__ x, const float* __restrict__ lw,
               const float* __restrict__ lb, u16t* __restrict__ xw) {
  int p = blockIdx.x * 256 + threadIdx.x;       // 0..50175
  int b = p / SPAT, s = p % SPAT;
  int d = s / 3136, r = s % 3136, h = r / 56, w = r % 56;
  const float* xp = x + (size_t)b * 96 * SPAT + s;
  float sum = 0.f, sq = 0.f;
  #pragma unroll 8
  for (int c = 0; c < 96; ++c) {
    float v = xp[(size_t)c * SPAT];
    sum += v; sq += v * v;
  }
  float mu = sum * (1.f / 96.f);
  float var = sq * (1.f / 96.f) - mu * mu;
  float rs = rsqrtf(var + 1e-5f);
  int ds = (d + 4) & 7;                          // (d-4) mod 8
  int hs = h - 3; if (hs < 0) hs += 56;
  int ws = w - 3; if (ws < 0) ws += 56;
  int win = b * 64 + (hs / 7) * 8 + (ws / 7);
  int n = ds * 49 + (hs % 7) * 7 + (ws % 7);
  u16t* op = xw + (size_t)(win * NTOK + n) * 96;
  #pragma unroll
  for (int g = 0; g < 12; ++g) {
    float v0 = xp[(size_t)(8 * g + 0) * SPAT], v1 = xp[(size_t)(8 * g + 1) * SPAT];
    float v2 = xp[(size_t)(8 * g + 2) * SPAT], v3 = xp[(size_t)(8 * g + 3) * SPAT];
    float v4 = xp[(size_t)(8 * g + 4) * SPAT], v5 = xp[(size_t)(8 * g + 5) * SPAT];
    float v6 = xp[(size_t)(8 * g + 6) * SPAT], v7 = xp[(size_t)(8 * g + 7) * SPAT];
    uint4 st;
    st.x = pack2((v0 - mu) * rs * lw[8*g+0] + lb[8*g+0], (v1 - mu) * rs * lw[8*g+1] + lb[8*g+1]);
    st.y = pack2((v2 - mu) * rs * lw[8*g+2] + lb[8*g+2], (v3 - mu) * rs * lw[8*g+3] + lb[8*g+3]);
    st.z = pack2((v4 - mu) * rs * lw[8*g+4] + lb[8*g+4], (v5 - mu) * rs * lw[8*g+5] + lb[8*g+5]);
    st.w = pack2((v6 - mu) * rs * lw[8*g+6] + lb[8*g+6], (v7 - mu) * rs * lw[8*g+7] + lb[8*g+7]);
    *reinterpret_cast<uint4*>(op + g * 8) = st;
  }
}

// ---------- kernel 2a: qkv weights -> bf16 (both heads) ----------
__global__ __launch_bounds__(256)
void k_qprep(const float* __restrict__ w0, const float* __restrict__ w1,
             u16t* __restrict__ wq) {
  int e = blockIdx.x * 256 + threadIdx.x;
  if (e >= 2 * 27648) return;
  wq[e] = (u16t)f2bf(e < 27648 ? w0[e] : w1[e - 27648]);
}

// ---------- kernel 2b: qkv GEMM via MFMA -> head-major dense [sel][head][tok][dh] ----------
template<int DH>
__global__ __launch_bounds__(256)
void k_qkv_mfma(const u16t* __restrict__ xw, const u16t* __restrict__ wq,
                const float* __restrict__ bias, u16t* __restrict__ qkvh) {
  int tid = threadIdx.x;
  int lane = tid & 63, wv = tid >> 6;
  int c = lane & 15, lg = lane >> 4;
  int t = blockIdx.x * 64 + wv * 16 + c;
  const u16t* bp = xw + (size_t)t * 96 + lg * 8;
  short8 bv[3];
  #pragma unroll
  for (int kc = 0; kc < 3; ++kc)
    bv[kc] = *reinterpret_cast<const short8*>(bp + kc * 32);
  f32x4 acc[18];
  #pragma unroll
  for (int f = 0; f < 18; ++f) acc[f] = (f32x4){0.f, 0.f, 0.f, 0.f};
  #pragma unroll
  for (int kc = 0; kc < 3; ++kc) {
    #pragma unroll
    for (int f = 0; f < 18; ++f) {
      short8 av = *reinterpret_cast<const short8*>(
          wq + (size_t)(f * 16 + c) * 96 + kc * 32 + lg * 8);
      acc[f] = __builtin_amdgcn_mfma_f32_16x16x32_bf16(av, bv[kc], acc[f], 0, 0, 0);
    }
  }
  #pragma unroll
  for (int f = 0; f < 18; ++f) {
    int co = f * 16 + lg * 4;
    float4 bb = *reinterpret_cast<const float4*>(bias + co);
    uint2 st = make_uint2(pack2(acc[f][0] + bb.x, acc[f][1] + bb.y),
                          pack2(acc[f][2] + bb.z, acc[f][3] + bb.w));
    int sel = co / 96, rem = co % 96;
    int head = rem / DH, dh = rem % DH;
    *reinterpret_cast<uint2*>(qkvh + (size_t)sel * NTOKTOT * 96
        + (size_t)head * NTOKTOT * DH + (size_t)t * DH + dh) = st;
  }
}

// ---------- kernel 2c: rpb -> per-head-contiguous bf16 [h][2536], pre-scaled by log2e ----------
template<int H>
__global__ __launch_bounds__(256)
void k_rprep(const float* __restrict__ rpb, u16t* __restrict__ rpbc) {
  int e = blockIdx.x * 256 + threadIdx.x;
  if (e >= H * 2536) return;
  int h = e / 2536, idx = e % 2536;
  rpbc[e] = (idx < 2535) ? (u16t)f2bf(rpb[idx * H + h] * LOG2E) : (u16t)0;
}

// ---------- kernel 3: MFMA window attention, online softmax (log2 domain), 8 waves ----------
// Region-disjoint tile PRE-skip (wave-uniform, before MFMA) + data-dependent post-skip.
template<int H, int DH>
__global__ __launch_bounds__(512, (DH == 16) ? 6 : 4)
void k_attn_mfma(const u16t* __restrict__ qkvh, const u16t* __restrict__ rpbc,
                 u16t* __restrict__ aout) {
  constexpr float SCALE2 = ((DH == 32) ? 0.17677669529663689f : 0.25f) * LOG2E;
  constexpr float MASKV = -100.f * LOG2E;
  constexpr float THR = 8.f * LOG2E;
  constexpr int NT = DH / 16;
  constexpr int QSPLIT = (DH == 16) ? 1 : 2;
  constexpr int KROW = (DH == 32) ? 32 : 16;
  constexpr int KS_U16 = (DH == 32) ? (416 * 32) : (417 * 16);  // DH16: extra zero row
  constexpr int BLK = 512;
  __shared__ __align__(16) u16t Ks[KS_U16];
  __shared__ __align__(16) u16t VTs[DH * 424];    // [dh][tok], stride 424
  __shared__ u16t rpbs[2536];                      // compact per-head bias (log2-scaled)
  __shared__ u16t Ts[416];                         // token coord codes (0 for pads)
  __shared__ u32t RGp[104];                        // packed region ids (255 for pads)
  __shared__ u32t RGm[26];                         // per-16-token-group region bitmask

  int bid = blockIdx.x;
  int xcd = bid & 7, i = bid >> 3;
  int win = xcd * 16 + (i & 15);
  int hp = i >> 4;
  int head = (DH == 32) ? (hp >> 1) : hp;
  int part = (DH == 32) ? (hp & 1) : 0;
  int wrem = win & 63;
  int hwin = wrem >> 3, wwin = wrem & 7;
  int tid = threadIdx.x;
  int lane = tid & 63, wv = tid >> 6;
  int c = lane & 15, lg = lane >> 4;

  const u16t* qh = qkvh + (size_t)head * NTOKTOT * DH + (size_t)win * NTOK * DH;
  const u16t* kh = qh + (size_t)NTOKTOT * 96;
  const u16t* vh = qh + (size_t)2 * NTOKTOT * 96;
  u16t* ao = aout + (size_t)head * NTOKTOT * DH + (size_t)win * NTOK * DH;

  {  // zero K/V (pads must be 0)
    uint4 z = make_uint4(0u, 0u, 0u, 0u);
    uint4* k4 = (uint4*)Ks;
    for (int i2 = tid; i2 < KS_U16 / 8; i2 += BLK) k4[i2] = z;
    uint4* v4 = (uint4*)VTs;
    for (int i2 = tid; i2 < (DH * 424) / 8; i2 += BLK) v4[i2] = z;
  }
  __syncthreads();
  constexpr int DG = DH / 8;
  for (int u = tid; u < NTOK * DG; u += BLK) {
    int j = u / DG, dg = u % DG;
    uint4 kv = *reinterpret_cast<const uint4*>(kh + (size_t)j * DH + dg * 8);
    int sch = (DH == 32) ? (dg ^ (j & 3)) : (dg ^ ((j & 1) ^ ((j >> 2) & 1)));
    *reinterpret_cast<uint4*>(&Ks[j * KROW + sch * 8]) = kv;
    union { uint4 q; u16t s[8]; } vv;
    vv.q = *reinterpret_cast<const uint4*>(vh + (size_t)j * DH + dg * 8);
    #pragma unroll
    for (int ee = 0; ee < 8; ++ee) VTs[(dg * 8 + ee) * 424 + j] = vv.s[ee];
  }
  for (int i2 = tid; i2 < 2536; i2 += BLK) rpbs[i2] = rpbc[head * 2536 + i2];
  for (int j = tid; j < 416; j += BLK) {
    u16t tv = 0;
    if (j < NTOK) {
      int ld = j / 49, r = j % 49, lh = r / 7, lw = r % 7;
      tv = (u16t)(ld * 169 + lh * 13 + lw);
    }
    Ts[j] = tv;
  }
  for (int j4 = tid; j4 < 104; j4 += BLK) {
    u32t w = 0;
    #pragma unroll
    for (int bb = 0; bb < 4; ++bb) {
      int j = j4 * 4 + bb;
      u32t rg = 255;
      if (j < NTOK) {
        int ld = j / 49, r = j % 49, lh = r / 7, lw = r % 7;
        int hpp = hwin * 7 + lh, wpp = wwin * 7 + lw;
        int rd = (ld < 4) ? 1 : 2;
        int rh = (hpp < 49) ? 0 : ((hpp < 53) ? 1 : 2);
        int rw = (wpp < 49) ? 0 : ((wpp < 53) ? 1 : 2);
        rg = (u32t)(rd * 9 + rh * 3 + rw);
      }
      w |= rg << (8 * bb);
    }
    RGp[j4] = w;
  }
  __syncthreads();
  if (tid < 26) {          // group region bitmask (27 region ids; pads add no bits)
    u32t msk = 0;
    #pragma unroll
    for (int j4 = 0; j4 < 4; ++j4) {
      u32t w = RGp[tid * 4 + j4];
      #pragma unroll
      for (int bb = 0; bb < 4; ++bb) {
        u32t rg = (w >> (8 * bb)) & 255u;
        if (rg < 27u) msk |= (1u << rg);
      }
    }
    RGm[tid] = msk;
  }
  __syncthreads();

  constexpr int QBASE = 25 / QSPLIT;
  constexpr int QREM = 25 % QSPLIT;
  int q0 = part * QBASE + ((part < QREM) ? part : QREM);
  int q1 = q0 + QBASE + ((part < QREM) ? 1 : 0);

  for (int qt = q0 + wv; qt < q1; qt += 8) {
    int qtok = qt * 16 + c;
    int qcl = (qtok < NTOK) ? qtok : NTOK - 1;
    int Tq = (int)Ts[qcl] + 1267;
    u32t rgq = (RGp[qcl >> 2] >> ((qcl & 3) * 8)) & 255u;
    u32t qmask = RGm[qt < 25 ? qt : 24];
    short8 bq;
    {
      const u16t* qp = qh + (size_t)qcl * DH;
      union { u32t u[4]; short8 v; } bu;
      #pragma unroll
      for (int i2 = 0; i2 < 4; ++i2) {
        u16t e0 = (DH == 32 || lg < 2) ? qp[lg * 8 + 2 * i2] : (u16t)0;
        u16t e1 = (DH == 32 || lg < 2) ? qp[lg * 8 + 2 * i2 + 1] : (u16t)0;
        bu.u[i2] = (u32t)e0 | ((u32t)e1 << 16);
      }
      bq = bu.v;
    }
    float m = -1e30f, lsum = 0.f;
    f32x4 oacc[NT];
    #pragma unroll
    for (int ot = 0; ot < NT; ++ot) oacc[ot] = (f32x4){0.f, 0.f, 0.f, 0.f};
    int srcl = ((lane >> 4) & 1) * 32 + c;
    #pragma unroll 1
    for (int tt = 0; tt < 13; ++tt) {
      // region-disjoint PRE-skip (wave-uniform): whole 16q x 32k tile masked
      u32t kmask = RGm[2 * tt] | ((2 * tt + 1 < 26) ? RGm[2 * tt + 1] : 0u);
      if ((qmask & kmask) == 0u) continue;
      f32x4 p0, p1;
      #pragma unroll
      for (int half = 0; half < 2; ++half) {
        int t = 2 * tt + half;
        int addr;
        if (DH == 32) {
          addr = (16 * t + c) * 32 + ((lg ^ (c & 3)) * 8);
        } else {
          int fc = (c & 1) ^ ((c >> 2) & 1);
          addr = (lg < 2) ? ((16 * t + c) * 16 + (((lg & 1) ^ fc) * 8)) : (416 * 16);
        }
        short8 av = *reinterpret_cast<const short8*>(&Ks[addr]);
        f32x4 a = (f32x4){0.f, 0.f, 0.f, 0.f};
        a = __builtin_amdgcn_mfma_f32_16x16x32_bf16(av, bq, a, 0, 0, 0);
        int kb = 16 * t + lg * 4;
        const u32t* tsp = reinterpret_cast<const u32t*>(&Ts[kb]);
        u32t tsa = tsp[0], tsb = tsp[1];
        u32t rgw = RGp[4 * t + lg];
        f32x4 p;
        p[0] = a[0] * SCALE2 + bflo((u32t)rpbs[Tq - (int)(tsa & 0xffffu)])
             + ((((rgw      ) & 255u) != rgq) ? MASKV : 0.f);
        p[1] = a[1] * SCALE2 + bflo((u32t)rpbs[Tq - (int)(tsa >> 16)])
             + ((((rgw >>  8) & 255u) != rgq) ? MASKV : 0.f);
        p[2] = a[2] * SCALE2 + bflo((u32t)rpbs[Tq - (int)(tsb & 0xffffu)])
             + ((((rgw >> 16) & 255u) != rgq) ? MASKV : 0.f);
        p[3] = a[3] * SCALE2 + bflo((u32t)rpbs[Tq - (int)(tsb >> 16)])
             + ((((rgw >> 24)        ) != rgq) ? MASKV : 0.f);
        if (half == 0) p0 = p; else p1 = p;
      }
      float pm = fmaxf(fmaxf(fmaxf(p0[0], p0[1]), fmaxf(p0[2], p0[3])),
                       fmaxf(fmaxf(p1[0], p1[1]), fmaxf(p1[2], p1[3])));
      pm = fmaxf(pm, __shfl_xor(pm, 16));
      pm = fmaxf(pm, __shfl_xor(pm, 32));
      bool dead = (pm <= m - 25.f) || (pm <= -90.f);
      if (__all(dead)) continue;
      if (!__all(pm <= m + THR)) {           // rescale only when some lane's max grew
        float mnew = fmaxf(pm, m);           // per-lane
        float fac = exp2v(m - mnew);
        lsum *= fac;
        #pragma unroll
        for (int ot = 0; ot < NT; ++ot) oacc[ot] *= fac;
        m = mnew;
      }
      #pragma unroll
      for (int j = 0; j < 4; ++j) {
        p0[j] = exp2v(p0[j] - m);
        p1[j] = exp2v(p1[j] - m);
      }
      lsum += p0[0] + p0[1] + p0[2] + p0[3] + p1[0] + p1[1] + p1[2] + p1[3];
      u32t pk0x = cvtpk(p0[0], p0[1]);
      u32t pk0y = cvtpk(p0[2], p0[3]);
      u32t pk1x = cvtpk(p1[0], p1[1]);
      u32t pk1y = cvtpk(p1[2], p1[3]);
      u32t ax = (u32t)__shfl((int)pk0x, srcl),      ay = (u32t)__shfl((int)pk0y, srcl);
      u32t bx = (u32t)__shfl((int)pk0x, srcl + 16), by = (u32t)__shfl((int)pk0y, srcl + 16);
      u32t cx = (u32t)__shfl((int)pk1x, srcl),      cy = (u32t)__shfl((int)pk1y, srcl);
      u32t dx = (u32t)__shfl((int)pk1x, srcl + 16), dy = (u32t)__shfl((int)pk1y, srcl + 16);
      bool hi = (lane & 32) != 0;
      union { u32t u[4]; short8 v; } au;
      au.u[0] = hi ? cx : ax; au.u[1] = hi ? cy : ay;
      au.u[2] = hi ? dx : bx; au.u[3] = hi ? dy : by;
      #pragma unroll
      for (int ot = 0; ot < NT; ++ot) {
        short8 bv = *reinterpret_cast<const short8*>(
            &VTs[(ot * 16 + c) * 424 + 32 * tt + lg * 8]);
        oacc[ot] = __builtin_amdgcn_mfma_f32_16x16x32_bf16(au.v, bv, oacc[ot], 0, 0, 0);
      }
    }
    lsum += __shfl_xor(lsum, 16);
    lsum += __shfl_xor(lsum, 32);
    float inv = 1.f / lsum;
    float invj[4];
    #pragma unroll
    for (int j = 0; j < 4; ++j) invj[j] = __shfl(inv, lg * 4 + j);
    #pragma unroll
    for (int j = 0; j < 4; ++j) {
      int q = qt * 16 + lg * 4 + j;
      if (q < NTOK) {
        #pragma unroll
        for (int ot = 0; ot < NT; ++ot)
          ao[(size_t)q * DH + ot * 16 + c] = (u16t)f2bf(oacc[ot][j] * invj[j]);
      }
    }
  }
}

// ---------- kernel 4a: combined proj weights (alpha folded), bf16 ----------
__global__ __launch_bounds__(256)
void k_pprep(const float* __restrict__ pw0, const float* __restrict__ pb0,
             const float* __restrict__ pw1, const float* __restrict__ pb1,
             const float* __restrict__ alpha,
             u16t* __restrict__ wp, float* __restrict__ bp) {
  int e = blockIdx.x * 256 + threadIdx.x;
  if (e >= WPROJ_N) return;
  float al0 = alpha[0], al1 = alpha[1];
  float m = fmaxf(al0, al1);
  float e0 = expf(al0 - m), e1 = expf(al1 - m);
  float aw0 = e0 / (e0 + e1), aw1 = e1 / (e0 + e1);
  int co = e / 192, k = e % 192;
  float v = (k < 96) ? aw0 * pw0[co * 96 + k] : aw1 * pw1[co * 96 + k - 96];
  wp[e] = (u16t)f2bf(v);
  if (e < 96) bp[e] = aw0 * pb0[e] + aw1 * pb1[e];
}

// ---------- kernel 4b: proj via MFMA + window reverse + unshift + residual ----------
__global__ __launch_bounds__(64)
void k_proj_mfma(const u16t* __restrict__ a0, const u16t* __restrict__ a1,
                 const u16t* __restrict__ wp, const float* __restrict__ bp,
                 const float* __restrict__ x, float* __restrict__ x1) {
  int lane = threadIdx.x;
  int c = lane & 15, lg = lane >> 4;
  int t = blockIdx.x * 16 + c;
  int win = t / NTOK, n = t % NTOK;
  int b = win >> 6, wrem = win & 63;
  int hwin = wrem >> 3, wwin = wrem & 7;
  int ld = n / 49, r = n % 49, lh = r / 7, lw = r % 7;
  int d = (ld + 4) & 7;
  int h = (hwin * 7 + lh + 3) % 56;
  int w = (wwin * 7 + lw + 3) % 56;
  size_t base = (size_t)b * 96 * SPAT + d * 3136 + h * 56 + w;

  f32x4 acc[6];
  #pragma unroll
  for (int f = 0; f < 6; ++f) acc[f] = (f32x4){0.f, 0.f, 0.f, 0.f};
  #pragma unroll
  for (int kc = 0; kc < 6; ++kc) {
    short8 bv;
    if (kc < 3) {
      bv = *reinterpret_cast<const short8*>(a0 + ((size_t)kc * NTOKTOT + t) * 32 + lg * 8);
    } else {
      int h1 = (kc - 3) * 2 + (lg >> 1);
      bv = *reinterpret_cast<const short8*>(a1 + ((size_t)h1 * NTOKTOT + t) * 16 + (lg & 1) * 8);
    }
    #pragma unroll
    for (int f = 0; f < 6; ++f) {
      short8 av = *reinterpret_cast<const short8*>(wp + (f * 16 + c) * 192 + kc * 32 + lg * 8);
      acc[f] = __builtin_amdgcn_mfma_f32_16x16x32_bf16(av, bv, acc[f], 0, 0, 0);
    }
  }
  #pragma unroll
  for (int f = 0; f < 6; ++f) {
    #pragma unroll
    for (int j = 0; j < 4; ++j) {
      int co = f * 16 + lg * 4 + j;
      size_t idx = base + (size_t)co * SPAT;
      x1[idx] = x[idx] + acc[f][j] + bp[co];
    }
  }
}

// ---------- kernel 5a: zero xpad ----------
__global__ __launch_bounds__(256)
void k_zero(uint4* __restrict__ p, int n) {
  int i = blockIdx.x * 256 + threadIdx.x;
  if (i < n) p[i] = make_uint4(0u, 0u, 0u, 0u);
}

// ---------- kernel 5b: combined FFN weights (softmax-alpha folded), bf16 ----------
__global__ __launch_bounds__(256)
void k_wprep(const float* __restrict__ c3w, const float* __restrict__ c3b,
             const float* __restrict__ c1w, const float* __restrict__ c1b,
             const float* __restrict__ dww, const float* __restrict__ dwb,
             const float* __restrict__ alpha,
             u16t* __restrict__ wcomb, float* __restrict__ bcomb) {
  int e = blockIdx.x * 256 + threadIdx.x;
  if (e >= WCOMB_N) return;
  float a0 = alpha[0], a1 = alpha[1], a2 = alpha[2], a3 = alpha[3];
  float mx = fmaxf(fmaxf(a0, a1), fmaxf(a2, a3));
  float e0 = expf(a0 - mx), e1 = expf(a1 - mx), e2 = expf(a2 - mx), e3 = expf(a3 - mx);
  float inv = 1.f / (e0 + e1 + e2 + e3);
  float f0 = e0 * inv, f1 = e1 * inv, f2 = e2 * inv, f3 = e3 * inv;
  int ko = e / 9216, rm = e % 9216, co = rm / 96, ci = rm % 96;
  float v = f0 * c3w[(co * 96 + ci) * 27 + ko];
  if (ko == 13) v += f1 * c1w[co * 96 + ci];
  if (ci == co) v += f2 * dww[co * 27 + ko];
  if (ko == 13 && ci == co) v += f3;
  wcomb[e] = (u16t)f2bf(v);
  if (e < 96) bcomb[e] = f0 * c3b[e] + f1 * c1b[e] + f2 * dwb[e];
}

// ---------- kernel 5c: LN2 -> padded CHANNEL-LAST bf16 tensor ----------
__global__ __launch_bounds__(256)
void k_ln2pad(const float* __restrict__ x1, const float* __restrict__ lw,
              const float* __restrict__ lb, u16t* __restrict__ xpad) {
  int p = blockIdx.x * 256 + threadIdx.x;       // 0..50175
  int b = p / SPAT, s = p % SPAT;
  int d = s / 3136, r = s % 3136, h = r / 56, w = r % 56;
  const float* xp = x1 + (size_t)b * 96 * SPAT + s;
  float sum = 0.f, sq = 0.f;
  #pragma unroll 8
  for (int c = 0; c < 96; ++c) {
    float v = xp[(size_t)c * SPAT];
    sum += v; sq += v * v;
  }
  float mu = sum * (1.f / 96.f);
  float var = sq * (1.f / 96.f) - mu * mu;
  float rs = rsqrtf(var + 1e-5f);
  int psp = ((b * 10 + d + 1) * 58 + (h + 1)) * 58 + (w + 1);
  u16t* op = xpad + (size_t)psp * 96;
  #pragma unroll
  for (int g = 0; g < 12; ++g) {
    float v0 = xp[(size_t)(8 * g + 0) * SPAT], v1 = xp[(size_t)(8 * g + 1) * SPAT];
    float v2 = xp[(size_t)(8 * g + 2) * SPAT], v3 = xp[(size_t)(8 * g + 3) * SPAT];
    float v4 = xp[(size_t)(8 * g + 4) * SPAT], v5 = xp[(size_t)(8 * g + 5) * SPAT];
    float v6 = xp[(size_t)(8 * g + 6) * SPAT], v7 = xp[(size_t)(8 * g + 7) * SPAT];
    uint4 st;
    st.x = pack2((v0 - mu) * rs * lw[8*g+0] + lb[8*g+0], (v1 - mu) * rs * lw[8*g+1] + lb[8*g+1]);
    st.y = pack2((v2 - mu) * rs * lw[8*g+2] + lb[8*g+2], (v3 - mu) * rs * lw[8*g+3] + lb[8*g+3]);
    st.z = pack2((v4 - mu) * rs * lw[8*g+4] + lb[8*g+4], (v5 - mu) * rs * lw[8*g+5] + lb[8*g+5]);
    st.w = pack2((v6 - mu) * rs * lw[8*g+6] + lb[8*g+6], (v7 - mu) * rs * lw[8*g+7] + lb[8*g+7]);
    *reinterpret_cast<uint4*>(op + g * 8) = st;
  }
}

// ---------- kernel 6: FFN implicit GEMM via MFMA (channel-last xpad) ----------
// 784 blocks = 2 co-halves x 392 sp-tiles; 8 waves x 512 thr.
// wls row stride 108 u16 (54 dwords == 22 mod 32): 16 lanes hit 16 distinct banks.
__global__ __launch_bounds__(512)
void k_ffn_mfma(const u16t* __restrict__ xpad, const u16t* __restrict__ wcomb,
                const float* __restrict__ bcomb, float* __restrict__ out) {
  __shared__ __align__(16) u16t wls[2][48 * 108];
  int tid = threadIdx.x;
  int lane = tid & 63, wv = tid >> 6;        // wv 0..7
  int c = lane & 15, kg = lane >> 4;
  int bid = blockIdx.x;
  int coh = bid & 1;                         // co half
  int sp = bid >> 1;                         // spatial tile 0..391
  int swz = (sp & 7) * 49 + (sp >> 3);       // bijective: 392 = 8*49
  int m = swz * 128 + wv * 16 + c;
  int b = m / SPAT, r = m % SPAT;
  int d = r / 3136, r2 = r % 3136, h = r2 / 56, w = r2 % 56;
  int psp0 = ((b * 10 + d) * 58 + h) * 58 + w;
  int pbase = psp0 * 96 + kg * 8;
  int obase = b * (96 * SPAT) + r;

  f32x4 acc[3];
  #pragma unroll
  for (int ff = 0; ff < 3; ++ff) acc[ff] = (f32x4){0.f, 0.f, 0.f, 0.f};

  {
    const uint4* src = (const uint4*)(wcomb) + coh * 576;
    for (int e = tid; e < 576; e += 512) {
      uint4 v = src[e];
      int lco = (e * 8) / 96, ci = (e * 8) % 96;
      *reinterpret_cast<uint4*>(&wls[0][lco * 108 + ci]) = v;
    }
  }
  __syncthreads();
  int buf = 0;
  for (int ko = 0; ko < 27; ++ko) {
    int kd = ko / 9, kh = (ko / 3) % 3, kw = ko % 3;
    int tapoff = (kd * PHW + kh * PW + kw) * 96;
    if (ko + 1 < 27) {
      const uint4* src = (const uint4*)(wcomb) + (ko + 1) * 1152 + coh * 576;
      for (int e = tid; e < 576; e += 512) {
        uint4 v = src[e];
        int lco = (e * 8) / 96, ci = (e * 8) % 96;
        *reinterpret_cast<uint4*>(&wls[buf ^ 1][lco * 108 + ci]) = v;
      }
    }
    #pragma unroll
    for (int cc = 0; cc < 3; ++cc) {
      short8 bv = *reinterpret_cast<const short8*>(xpad + pbase + tapoff + cc * 32);
      #pragma unroll
      for (int ff = 0; ff < 3; ++ff) {
        short8 av = *reinterpret_cast<const short8*>(
            &wls[buf][(ff * 16 + c) * 108 + cc * 32 + kg * 8]);
        acc[ff] = __builtin_amdgcn_mfma_f32_16x16x32_bf16(av, bv, acc[ff], 0, 0, 0);
      }
    }
    __syncthreads();
    buf ^= 1;
  }
  #pragma unroll
  for (int ff = 0; ff < 3; ++ff)
    #pragma unroll
    for (int j = 0; j < 4; ++j) {
      int co = coh * 48 + ff * 16 + kg * 4 + j;
      float* o = out + obase + co * SPAT;
      *o = *o + acc[ff][j] + bcomb[co];
    }
}

extern "C" void kernel_launch(void* const* d_in, const int* in_sizes, int n_in,
                              void* d_out, int out_size, void* d_ws, size_t ws_size,
                              hipStream_t stream) {
  (void)in_sizes; (void)n_in; (void)out_size; (void)ws_size;
  const float* x      = (const float*)d_in[0];
  const float* ln1w   = (const float*)d_in[1];
  const float* ln1b   = (const float*)d_in[2];
  const float* ln2w   = (const float*)d_in[3];
  const float* ln2b   = (const float*)d_in[4];
  const float* qkvw0  = (const float*)d_in[5];
  const float* qkvb0  = (const float*)d_in[6];
  const float* projw0 = (const float*)d_in[7];
  const float* projb0 = (const float*)d_in[8];
  const float* rpb0   = (const float*)d_in[9];
  const float* qkvw1  = (const float*)d_in[10];
  const float* qkvb1  = (const float*)d_in[11];
  const float* projw1 = (const float*)d_in[12];
  const float* projb1 = (const float*)d_in[13];
  const float* rpb1   = (const float*)d_in[14];
  const float* aattn  = (const float*)d_in[15];
  const float* c3w    = (const float*)d_in[16];
  const float* c3b    = (const float*)d_in[17];
  const float* c1w    = (const float*)d_in[18];
  const float* c1b    = (const float*)d_in[19];
  const float* dww    = (const float*)d_in[20];
  const float* dwb    = (const float*)d_in[21];
  const float* affn   = (const float*)d_in[22];

  // workspace (u16 units)
  u16t* u    = (u16t*)d_ws;
  u16t* xw   = u;                                  // 50176*96
  u16t* a0   = xw + (size_t)NTOKTOT * 96;          // 3*50176*32
  u16t* a1   = a0 + (size_t)3 * NTOKTOT * 32;      // 6*50176*16
  u16t* qkvh = a1 + (size_t)6 * NTOKTOT * 16;      // 3*50176*96 (q|k|v head-major)
  u16t* wq   = qkvh + (size_t)3 * NTOKTOT * 96;    // 2*27648
  u16t* rpbc0 = wq + 2 * 27648;                    // 3*2536
  u16t* rpbc1 = rpbc0 + 3 * 2536;                  // 6*2536
  u16t* xpad  = qkvh;                              // reuse (dead after attn), channel-last
  u16t* wcomb = xpad + XPAD_U16;
  float* bcomb = (float*)(wcomb + WCOMB_N);
  u16t* wproj = (u16t*)(bcomb + 96);
  float* bproj = (float*)(wproj + WPROJ_N);
  float* x1  = (float*)d_out;

  k_ln1_win<<<196, 256, 0, stream>>>(x, ln1w, ln1b, xw);
  k_qprep<<<216, 256, 0, stream>>>(qkvw0, qkvw1, wq);
  k_rprep<3><<<30, 256, 0, stream>>>(rpb0, rpbc0);
  k_rprep<6><<<60, 256, 0, stream>>>(rpb1, rpbc1);
  k_qkv_mfma<32><<<784, 256, 0, stream>>>(xw, wq, qkvb0, qkvh);
  k_attn_mfma<3, 32><<<768, 512, 0, stream>>>(qkvh, rpbc0, a0);
  k_qkv_mfma<16><<<784, 256, 0, stream>>>(xw, wq + 27648, qkvb1, qkvh);
  k_attn_mfma<6, 16><<<768, 512, 0, stream>>>(qkvh, rpbc1, a1);
  // qkvh dead: build xpad / combined weights in its place
  k_zero<<<(XPAD_U16 / 8 + 255) / 256, 256, 0, stream>>>((uint4*)xpad, XPAD_U16 / 8);
  k_wprep<<<(WCOMB_N + 255) / 256, 256, 0, stream>>>(c3w, c3b, c1w, c1b, dww, dwb,
                                                     affn, wcomb, bcomb);
  k_pprep<<<(WPROJ_N + 255) / 256, 256, 0, stream>>>(projw0, projb0, projw1, projb1,
                                                     aattn, wproj, bproj);
  k_proj_mfma<<<3136, 64, 0, stream>>>(a0, a1, wproj, bproj, x, x1);
  k_ln2pad<<<196, 256, 0, stream>>>(x1, ln2w, ln2b, xpad);
  k_ffn_mfma<<<784, 512, 0, stream>>>(xpad, wcomb, bcomb, (float*)d_out);
}

// Round 28
// 268.926 us; speedup vs baseline: 1.3638x; 1.0041x over previous
//
#include <hip/hip_runtime.h>

#define NWIN 128       // B * nW windows
#define NTOK 392       // tokens per window (8*7*7)
#define SPAT 25088     // D*H*W
#define NELEM 4816896  // 2*96*25088

typedef unsigned short u16t;
typedef unsigned int u32t;
typedef __attribute__((ext_vector_type(8))) short short8;
typedef __attribute__((ext_vector_type(4))) float f32x4;

// xpad geometry: CHANNEL-LAST [b][10][58][58][96] bf16, zero border
#define PW 58
#define PHW 3364      // 58*58
#define PSPAT 33640   // 10*58*58
#define XPAD_U16 6458880   // 2*33640*96
#define WCOMB_N 248832     // 27*96*96
#define WPROJ_N 18432      // 96*192
#define NTOKTOT 50176      // NWIN*NTOK
#define LOG2E 1.44269504f

// ---------- helpers ----------
__device__ __forceinline__ unsigned int f2bf(float f) {
  unsigned int u = __float_as_uint(f);
  return (u + 0x7fffu + ((u >> 16) & 1u)) >> 16;   // RNE to bf16
}
__device__ __forceinline__ unsigned int pack2(float a, float b) {
  return f2bf(a) | (f2bf(b) << 16);
}
__device__ __forceinline__ u32t cvtpk(float lo, float hi) {
  u32t r;
  asm("v_cvt_pk_bf16_f32 %0, %1, %2" : "=v"(r) : "v"(lo), "v"(hi));
  return r;
}
__device__ __forceinline__ float exp2v(float x) {
  return __builtin_amdgcn_exp2f(x);   // raw v_exp_f32 (2^x)
}
__device__ __forceinline__ float bflo(unsigned int u) { return __uint_as_float(u << 16); }

// ---------- kernel 1: LN1 over C + roll(-4,-3,-3) + window partition (bf16 out) ----------
__global__ __launch_bounds__(256)
void k_ln1_win(const float* __restrict__ x, const float* __restrict__ lw,
               const float* __restrict__ lb, u16t* __restrict__ xw) {
  int p = blockIdx.x * 256 + threadIdx.x;       // 0..50175
  int b = p / SPAT, s = p % SPAT;
  int d = s / 3136, r = s % 3136, h = r / 56, w = r % 56;
  const float* xp = x + (size_t)b * 96 * SPAT + s;
  float sum = 0.f, sq = 0.f;
  #pragma unroll 8
  for (int c = 0; c < 96; ++c) {
    float v = xp[(size_t)c * SPAT];
    sum += v; sq += v * v;
  }
  float mu = sum * (1.f / 96.f);
  float var = sq * (1.f / 96.f) - mu * mu;
  float rs = rsqrtf(var + 1e-5f);
  int ds = (d + 4) & 7;                          // (d-4) mod 8
  int hs = h - 3; if (hs < 0) hs += 56;
  int ws = w - 3; if (ws < 0) ws += 56;
  int win = b * 64 + (hs / 7) * 8 + (ws / 7);
  int n = ds * 49 + (hs % 7) * 7 + (ws % 7);
  u16t* op = xw + (size_t)(win * NTOK + n) * 96;
  #pragma unroll
  for (int g = 0; g < 12; ++g) {
    float v0 = xp[(size_t)(8 * g + 0) * SPAT], v1 = xp[(size_t)(8 * g + 1) * SPAT];
    float v2 = xp[(size_t)(8 * g + 2) * SPAT], v3 = xp[(size_t)(8 * g + 3) * SPAT];
    float v4 = xp[(size_t)(8 * g + 4) * SPAT], v5 = xp[(size_t)(8 * g + 5) * SPAT];
    float v6 = xp[(size_t)(8 * g + 6) * SPAT], v7 = xp[(size_t)(8 * g + 7) * SPAT];
    uint4 st;
    st.x = pack2((v0 - mu) * rs * lw[8*g+0] + lb[8*g+0], (v1 - mu) * rs * lw[8*g+1] + lb[8*g+1]);
    st.y = pack2((v2 - mu) * rs * lw[8*g+2] + lb[8*g+2], (v3 - mu) * rs * lw[8*g+3] + lb[8*g+3]);
    st.z = pack2((v4 - mu) * rs * lw[8*g+4] + lb[8*g+4], (v5 - mu) * rs * lw[8*g+5] + lb[8*g+5]);
    st.w = pack2((v6 - mu) * rs * lw[8*g+6] + lb[8*g+6], (v7 - mu) * rs * lw[8*g+7] + lb[8*g+7]);
    *reinterpret_cast<uint4*>(op + g * 8) = st;
  }
}

// ---------- kernel 2a: qkv weights -> bf16 (both heads) ----------
__global__ __launch_bounds__(256)
void k_qprep(const float* __restrict__ w0, const float* __restrict__ w1,
             u16t* __restrict__ wq) {
  int e = blockIdx.x * 256 + threadIdx.x;
  if (e >= 2 * 27648) return;
  wq[e] = (u16t)f2bf(e < 27648 ? w0[e] : w1[e - 27648]);
}

// ---------- kernel 2b: qkv GEMM via MFMA -> head-major dense [sel][head][tok][dh] ----------
template<int DH>
__global__ __launch_bounds__(256)
void k_qkv_mfma(const u16t* __restrict__ xw, const u16t* __restrict__ wq,
                const float* __restrict__ bias, u16t* __restrict__ qkvh) {
  int tid = threadIdx.x;
  int lane = tid & 63, wv = tid >> 6;
  int c = lane & 15, lg = lane >> 4;
  int t = blockIdx.x * 64 + wv * 16 + c;
  const u16t* bp = xw + (size_t)t * 96 + lg * 8;
  short8 bv[3];
  #pragma unroll
  for (int kc = 0; kc < 3; ++kc)
    bv[kc] = *reinterpret_cast<const short8*>(bp + kc * 32);
  f32x4 acc[18];
  #pragma unroll
  for (int f = 0; f < 18; ++f) acc[f] = (f32x4){0.f, 0.f, 0.f, 0.f};
  #pragma unroll
  for (int kc = 0; kc < 3; ++kc) {
    #pragma unroll
    for (int f = 0; f < 18; ++f) {
      short8 av = *reinterpret_cast<const short8*>(
          wq + (size_t)(f * 16 + c) * 96 + kc * 32 + lg * 8);
      acc[f] = __builtin_amdgcn_mfma_f32_16x16x32_bf16(av, bv[kc], acc[f], 0, 0, 0);
    }
  }
  #pragma unroll
  for (int f = 0; f < 18; ++f) {
    int co = f * 16 + lg * 4;
    float4 bb = *reinterpret_cast<const float4*>(bias + co);
    uint2 st = make_uint2(pack2(acc[f][0] + bb.x, acc[f][1] + bb.y),
                          pack2(acc[f][2] + bb.z, acc[f][3] + bb.w));
    int sel = co / 96, rem = co % 96;
    int head = rem / DH, dh = rem % DH;
    *reinterpret_cast<uint2*>(qkvh + (size_t)sel * NTOKTOT * 96
        + (size_t)head * NTOKTOT * DH + (size_t)t * DH + dh) = st;
  }
}

// ---------- kernel 2c: rpb -> per-head-contiguous bf16 [h][2536], pre-scaled by log2e ----------
template<int H>
__global__ __launch_bounds__(256)
void k_rprep(const float* __restrict__ rpb, u16t* __restrict__ rpbc) {
  int e = blockIdx.x * 256 + threadIdx.x;
  if (e >= H * 2536) return;
  int h = e / 2536, idx = e % 2536;
  rpbc[e] = (idx < 2535) ? (u16t)f2bf(rpb[idx * H + h] * LOG2E) : (u16t)0;
}

// ---------- kernel 3: MFMA window attention, online softmax (log2 domain), 8 waves ----------
// Region-disjoint tile PRE-skip (wave-uniform, before MFMA) + data-dependent post-skip.
template<int H, int DH>
__global__ __launch_bounds__(512, (DH == 16) ? 6 : 4)
void k_attn_mfma(const u16t* __restrict__ qkvh, const u16t* __restrict__ rpbc,
                 u16t* __restrict__ aout) {
  constexpr float SCALE2 = ((DH == 32) ? 0.17677669529663689f : 0.25f) * LOG2E;
  constexpr float MASKV = -100.f * LOG2E;
  constexpr float THR = 8.f * LOG2E;
  constexpr int NT = DH / 16;
  constexpr int QSPLIT = (DH == 16) ? 1 : 2;
  constexpr int KROW = (DH == 32) ? 32 : 16;
  constexpr int KS_U16 = (DH == 32) ? (416 * 32) : (417 * 16);  // DH16: extra zero row
  constexpr int BLK = 512;
  __shared__ __align__(16) u16t Ks[KS_U16];
  __shared__ __align__(16) u16t VTs[DH * 424];    // [dh][tok], stride 424
  __shared__ u16t rpbs[2536];                      // compact per-head bias (log2-scaled)
  __shared__ u16t Ts[416];                         // token coord codes (0 for pads)
  __shared__ u32t RGp[104];                        // packed region ids (255 for pads)
  __shared__ u32t RGm[26];                         // per-16-token-group region bitmask

  int bid = blockIdx.x;
  int xcd = bid & 7, i = bid >> 3;
  int win = xcd * 16 + (i & 15);
  int hp = i >> 4;
  int head = (DH == 32) ? (hp >> 1) : hp;
  int part = (DH == 32) ? (hp & 1) : 0;
  int wrem = win & 63;
  int hwin = wrem >> 3, wwin = wrem & 7;
  int tid = threadIdx.x;
  int lane = tid & 63, wv = tid >> 6;
  int c = lane & 15, lg = lane >> 4;

  const u16t* qh = qkvh + (size_t)head * NTOKTOT * DH + (size_t)win * NTOK * DH;
  const u16t* kh = qh + (size_t)NTOKTOT * 96;
  const u16t* vh = qh + (size_t)2 * NTOKTOT * 96;
  u16t* ao = aout + (size_t)head * NTOKTOT * DH + (size_t)win * NTOK * DH;

  {  // zero K/V (pads must be 0)
    uint4 z = make_uint4(0u, 0u, 0u, 0u);
    uint4* k4 = (uint4*)Ks;
    for (int i2 = tid; i2 < KS_U16 / 8; i2 += BLK) k4[i2] = z;
    uint4* v4 = (uint4*)VTs;
    for (int i2 = tid; i2 < (DH * 424) / 8; i2 += BLK) v4[i2] = z;
  }
  __syncthreads();
  constexpr int DG = DH / 8;
  for (int u = tid; u < NTOK * DG; u += BLK) {
    int j = u / DG, dg = u % DG;
    uint4 kv = *reinterpret_cast<const uint4*>(kh + (size_t)j * DH + dg * 8);
    int sch = (DH == 32) ? (dg ^ (j & 3)) : (dg ^ ((j & 1) ^ ((j >> 2) & 1)));
    *reinterpret_cast<uint4*>(&Ks[j * KROW + sch * 8]) = kv;
    union { uint4 q; u16t s[8]; } vv;
    vv.q = *reinterpret_cast<const uint4*>(vh + (size_t)j * DH + dg * 8);
    #pragma unroll
    for (int ee = 0; ee < 8; ++ee) VTs[(dg * 8 + ee) * 424 + j] = vv.s[ee];
  }
  for (int i2 = tid; i2 < 2536; i2 += BLK) rpbs[i2] = rpbc[head * 2536 + i2];
  for (int j = tid; j < 416; j += BLK) {
    u16t tv = 0;
    if (j < NTOK) {
      int ld = j / 49, r = j % 49, lh = r / 7, lw = r % 7;
      tv = (u16t)(ld * 169 + lh * 13 + lw);
    }
    Ts[j] = tv;
  }
  for (int j4 = tid; j4 < 104; j4 += BLK) {
    u32t w = 0;
    #pragma unroll
    for (int bb = 0; bb < 4; ++bb) {
      int j = j4 * 4 + bb;
      u32t rg = 255;
      if (j < NTOK) {
        int ld = j / 49, r = j % 49, lh = r / 7, lw = r % 7;
        int hpp = hwin * 7 + lh, wpp = wwin * 7 + lw;
        int rd = (ld < 4) ? 1 : 2;
        int rh = (hpp < 49) ? 0 : ((hpp < 53) ? 1 : 2);
        int rw = (wpp < 49) ? 0 : ((wpp < 53) ? 1 : 2);
        rg = (u32t)(rd * 9 + rh * 3 + rw);
      }
      w |= rg << (8 * bb);
    }
    RGp[j4] = w;
  }
  __syncthreads();
  if (tid < 26) {          // group region bitmask (27 region ids; pads add no bits)
    u32t msk = 0;
    #pragma unroll
    for (int j4 = 0; j4 < 4; ++j4) {
      u32t w = RGp[tid * 4 + j4];
      #pragma unroll
      for (int bb = 0; bb < 4; ++bb) {
        u32t rg = (w >> (8 * bb)) & 255u;
        if (rg < 27u) msk |= (1u << rg);
      }
    }
    RGm[tid] = msk;
  }
  __syncthreads();

  constexpr int QBASE = 25 / QSPLIT;
  constexpr int QREM = 25 % QSPLIT;
  int q0 = part * QBASE + ((part < QREM) ? part : QREM);
  int q1 = q0 + QBASE + ((part < QREM) ? 1 : 0);

  for (int qt = q0 + wv; qt < q1; qt += 8) {
    int qtok = qt * 16 + c;
    int qcl = (qtok < NTOK) ? qtok : NTOK - 1;
    int Tq = (int)Ts[qcl] + 1267;
    u32t rgq = (RGp[qcl >> 2] >> ((qcl & 3) * 8)) & 255u;
    u32t qmask = RGm[qt < 25 ? qt : 24];
    short8 bq;
    {
      const u16t* qp = qh + (size_t)qcl * DH;
      union { u32t u[4]; short8 v; } bu;
      #pragma unroll
      for (int i2 = 0; i2 < 4; ++i2) {
        u16t e0 = (DH == 32 || lg < 2) ? qp[lg * 8 + 2 * i2] : (u16t)0;
        u16t e1 = (DH == 32 || lg < 2) ? qp[lg * 8 + 2 * i2 + 1] : (u16t)0;
        bu.u[i2] = (u32t)e0 | ((u32t)e1 << 16);
      }
      bq = bu.v;
    }
    float m = -1e30f, lsum = 0.f;
    f32x4 oacc[NT];
    #pragma unroll
    for (int ot = 0; ot < NT; ++ot) oacc[ot] = (f32x4){0.f, 0.f, 0.f, 0.f};
    int srcl = ((lane >> 4) & 1) * 32 + c;
    #pragma unroll 1
    for (int tt = 0; tt < 13; ++tt) {
      // region-disjoint PRE-skip (wave-uniform): whole 16q x 32k tile masked
      u32t kmask = RGm[2 * tt] | ((2 * tt + 1 < 26) ? RGm[2 * tt + 1] : 0u);
      if ((qmask & kmask) == 0u) continue;
      f32x4 p0, p1;
      #pragma unroll
      for (int half = 0; half < 2; ++half) {
        int t = 2 * tt + half;
        int addr;
        if (DH == 32) {
          addr = (16 * t + c) * 32 + ((lg ^ (c & 3)) * 8);
        } else {
          int fc = (c & 1) ^ ((c >> 2) & 1);
          addr = (lg < 2) ? ((16 * t + c) * 16 + (((lg & 1) ^ fc) * 8)) : (416 * 16);
        }
        short8 av = *reinterpret_cast<const short8*>(&Ks[addr]);
        f32x4 a = (f32x4){0.f, 0.f, 0.f, 0.f};
        a = __builtin_amdgcn_mfma_f32_16x16x32_bf16(av, bq, a, 0, 0, 0);
        int kb = 16 * t + lg * 4;
        const u32t* tsp = reinterpret_cast<const u32t*>(&Ts[kb]);
        u32t tsa = tsp[0], tsb = tsp[1];
        u32t rgw = RGp[4 * t + lg];
        f32x4 p;
        p[0] = a[0] * SCALE2 + bflo((u32t)rpbs[Tq - (int)(tsa & 0xffffu)])
             + ((((rgw      ) & 255u) != rgq) ? MASKV : 0.f);
        p[1] = a[1] * SCALE2 + bflo((u32t)rpbs[Tq - (int)(tsa >> 16)])
             + ((((rgw >>  8) & 255u) != rgq) ? MASKV : 0.f);
        p[2] = a[2] * SCALE2 + bflo((u32t)rpbs[Tq - (int)(tsb & 0xffffu)])
             + ((((rgw >> 16) & 255u) != rgq) ? MASKV : 0.f);
        p[3] = a[3] * SCALE2 + bflo((u32t)rpbs[Tq - (int)(tsb >> 16)])
             + ((((rgw >> 24)        ) != rgq) ? MASKV : 0.f);
        if (half == 0) p0 = p; else p1 = p;
      }
      float pm = fmaxf(fmaxf(fmaxf(p0[0], p0[1]), fmaxf(p0[2], p0[3])),
                       fmaxf(fmaxf(p1[0], p1[1]), fmaxf(p1[2], p1[3])));
      pm = fmaxf(pm, __shfl_xor(pm, 16));
      pm = fmaxf(pm, __shfl_xor(pm, 32));
      bool dead = (pm <= m - 25.f) || (pm <= -90.f);
      if (__all(dead)) continue;
      if (!__all(pm <= m + THR)) {           // rescale only when some lane's max grew
        float mnew = fmaxf(pm, m);           // per-lane
        float fac = exp2v(m - mnew);
        lsum *= fac;
        #pragma unroll
        for (int ot = 0; ot < NT; ++ot) oacc[ot] *= fac;
        m = mnew;
      }
      #pragma unroll
      for (int j = 0; j < 4; ++j) {
        p0[j] = exp2v(p0[j] - m);
        p1[j] = exp2v(p1[j] - m);
      }
      lsum += p0[0] + p0[1] + p0[2] + p0[3] + p1[0] + p1[1] + p1[2] + p1[3];
      u32t pk0x = cvtpk(p0[0], p0[1]);
      u32t pk0y = cvtpk(p0[2], p0[3]);
      u32t pk1x = cvtpk(p1[0], p1[1]);
      u32t pk1y = cvtpk(p1[2], p1[3]);
      u32t ax = (u32t)__shfl((int)pk0x, srcl),      ay = (u32t)__shfl((int)pk0y, srcl);
      u32t bx = (u32t)__shfl((int)pk0x, srcl + 16), by = (u32t)__shfl((int)pk0y, srcl + 16);
      u32t cx = (u32t)__shfl((int)pk1x, srcl),      cy = (u32t)__shfl((int)pk1y, srcl);
      u32t dx = (u32t)__shfl((int)pk1x, srcl + 16), dy = (u32t)__shfl((int)pk1y, srcl + 16);
      bool hi = (lane & 32) != 0;
      union { u32t u[4]; short8 v; } au;
      au.u[0] = hi ? cx : ax; au.u[1] = hi ? cy : ay;
      au.u[2] = hi ? dx : bx; au.u[3] = hi ? dy : by;
      #pragma unroll
      for (int ot = 0; ot < NT; ++ot) {
        short8 bv = *reinterpret_cast<const short8*>(
            &VTs[(ot * 16 + c) * 424 + 32 * tt + lg * 8]);
        oacc[ot] = __builtin_amdgcn_mfma_f32_16x16x32_bf16(au.v, bv, oacc[ot], 0, 0, 0);
      }
    }
    lsum += __shfl_xor(lsum, 16);
    lsum += __shfl_xor(lsum, 32);
    float inv = 1.f / lsum;
    float invj[4];
    #pragma unroll
    for (int j = 0; j < 4; ++j) invj[j] = __shfl(inv, lg * 4 + j);
    #pragma unroll
    for (int j = 0; j < 4; ++j) {
      int q = qt * 16 + lg * 4 + j;
      if (q < NTOK) {
        #pragma unroll
        for (int ot = 0; ot < NT; ++ot)
          ao[(size_t)q * DH + ot * 16 + c] = (u16t)f2bf(oacc[ot][j] * invj[j]);
      }
    }
  }
}

// ---------- kernel 4a: combined proj weights (alpha folded), bf16 ----------
__global__ __launch_bounds__(256)
void k_pprep(const float* __restrict__ pw0, const float* __restrict__ pb0,
             const float* __restrict__ pw1, const float* __restrict__ pb1,
             const float* __restrict__ alpha,
             u16t* __restrict__ wp, float* __restrict__ bp) {
  int e = blockIdx.x * 256 + threadIdx.x;
  if (e >= WPROJ_N) return;
  float al0 = alpha[0], al1 = alpha[1];
  float m = fmaxf(al0, al1);
  float e0 = expf(al0 - m), e1 = expf(al1 - m);
  float aw0 = e0 / (e0 + e1), aw1 = e1 / (e0 + e1);
  int co = e / 192, k = e % 192;
  float v = (k < 96) ? aw0 * pw0[co * 96 + k] : aw1 * pw1[co * 96 + k - 96];
  wp[e] = (u16t)f2bf(v);
  if (e < 96) bp[e] = aw0 * pb0[e] + aw1 * pb1[e];
}

// ---------- kernel 4b: proj via MFMA + window reverse + unshift + residual ----------
// 4-wave blocks (64 tokens), wproj staged in LDS (stride 204 u16 = 102 dw == 6 mod 32:
// 6c mod 32 distinct for c=0..15 -> bank-conflict-free A reads).
__global__ __launch_bounds__(256)
void k_proj_mfma(const u16t* __restrict__ a0, const u16t* __restrict__ a1,
                 const u16t* __restrict__ wp, const float* __restrict__ bp,
                 const float* __restrict__ x, float* __restrict__ x1) {
  __shared__ __align__(16) u16t wls[96 * 204];
  int tid = threadIdx.x;
  int lane = tid & 63, wv = tid >> 6;
  int c = lane & 15, lg = lane >> 4;
  for (int e = tid; e < 2304; e += 256) {       // 2304 uint4 = 96*192/8
    uint4 v = ((const uint4*)wp)[e];
    int row = (e * 8) / 192, col = (e * 8) % 192;
    *reinterpret_cast<uint4*>(&wls[row * 204 + col]) = v;
  }
  __syncthreads();

  int t = blockIdx.x * 64 + wv * 16 + c;
  int win = t / NTOK, n = t % NTOK;
  int b = win >> 6, wrem = win & 63;
  int hwin = wrem >> 3, wwin = wrem & 7;
  int ld = n / 49, r = n % 49, lh = r / 7, lw = r % 7;
  int d = (ld + 4) & 7;
  int h = (hwin * 7 + lh + 3) % 56;
  int w = (wwin * 7 + lw + 3) % 56;
  size_t base = (size_t)b * 96 * SPAT + d * 3136 + h * 56 + w;

  f32x4 acc[6];
  #pragma unroll
  for (int f = 0; f < 6; ++f) acc[f] = (f32x4){0.f, 0.f, 0.f, 0.f};
  #pragma unroll
  for (int kc = 0; kc < 6; ++kc) {
    short8 bv;
    if (kc < 3) {
      bv = *reinterpret_cast<const short8*>(a0 + ((size_t)kc * NTOKTOT + t) * 32 + lg * 8);
    } else {
      int h1 = (kc - 3) * 2 + (lg >> 1);
      bv = *reinterpret_cast<const short8*>(a1 + ((size_t)h1 * NTOKTOT + t) * 16 + (lg & 1) * 8);
    }
    #pragma unroll
    for (int f = 0; f < 6; ++f) {
      short8 av = *reinterpret_cast<const short8*>(
          &wls[(f * 16 + c) * 204 + kc * 32 + lg * 8]);
      acc[f] = __builtin_amdgcn_mfma_f32_16x16x32_bf16(av, bv, acc[f], 0, 0, 0);
    }
  }
  #pragma unroll
  for (int f = 0; f < 6; ++f) {
    #pragma unroll
    for (int j = 0; j < 4; ++j) {
      int co = f * 16 + lg * 4 + j;
      size_t idx = base + (size_t)co * SPAT;
      x1[idx] = x[idx] + acc[f][j] + bp[co];
    }
  }
}

// ---------- kernel 5a: zero xpad ----------
__global__ __launch_bounds__(256)
void k_zero(uint4* __restrict__ p, int n) {
  int i = blockIdx.x * 256 + threadIdx.x;
  if (i < n) p[i] = make_uint4(0u, 0u, 0u, 0u);
}

// ---------- kernel 5b: combined FFN weights (softmax-alpha folded), bf16 ----------
__global__ __launch_bounds__(256)
void k_wprep(const float* __restrict__ c3w, const float* __restrict__ c3b,
             const float* __restrict__ c1w, const float* __restrict__ c1b,
             const float* __restrict__ dww, const float* __restrict__ dwb,
             const float* __restrict__ alpha,
             u16t* __restrict__ wcomb, float* __restrict__ bcomb) {
  int e = blockIdx.x * 256 + threadIdx.x;
  if (e >= WCOMB_N) return;
  float a0 = alpha[0], a1 = alpha[1], a2 = alpha[2], a3 = alpha[3];
  float mx = fmaxf(fmaxf(a0, a1), fmaxf(a2, a3));
  float e0 = expf(a0 - mx), e1 = expf(a1 - mx), e2 = expf(a2 - mx), e3 = expf(a3 - mx);
  float inv = 1.f / (e0 + e1 + e2 + e3);
  float f0 = e0 * inv, f1 = e1 * inv, f2 = e2 * inv, f3 = e3 * inv;
  int ko = e / 9216, rm = e % 9216, co = rm / 96, ci = rm % 96;
  float v = f0 * c3w[(co * 96 + ci) * 27 + ko];
  if (ko == 13) v += f1 * c1w[co * 96 + ci];
  if (ci == co) v += f2 * dww[co * 27 + ko];
  if (ko == 13 && ci == co) v += f3;
  wcomb[e] = (u16t)f2bf(v);
  if (e < 96) bcomb[e] = f0 * c3b[e] + f1 * c1b[e] + f2 * dwb[e];
}

// ---------- kernel 5c: LN2 -> padded CHANNEL-LAST bf16 tensor ----------
__global__ __launch_bounds__(256)
void k_ln2pad(const float* __restrict__ x1, const float* __restrict__ lw,
              const float* __restrict__ lb, u16t* __restrict__ xpad) {
  int p = blockIdx.x * 256 + threadIdx.x;       // 0..50175
  int b = p / SPAT, s = p % SPAT;
  int d = s / 3136, r = s % 3136, h = r / 56, w = r % 56;
  const float* xp = x1 + (size_t)b * 96 * SPAT + s;
  float sum = 0.f, sq = 0.f;
  #pragma unroll 8
  for (int c = 0; c < 96; ++c) {
    float v = xp[(size_t)c * SPAT];
    sum += v; sq += v * v;
  }
  float mu = sum * (1.f / 96.f);
  float var = sq * (1.f / 96.f) - mu * mu;
  float rs = rsqrtf(var + 1e-5f);
  int psp = ((b * 10 + d + 1) * 58 + (h + 1)) * 58 + (w + 1);
  u16t* op = xpad + (size_t)psp * 96;
  #pragma unroll
  for (int g = 0; g < 12; ++g) {
    float v0 = xp[(size_t)(8 * g + 0) * SPAT], v1 = xp[(size_t)(8 * g + 1) * SPAT];
    float v2 = xp[(size_t)(8 * g + 2) * SPAT], v3 = xp[(size_t)(8 * g + 3) * SPAT];
    float v4 = xp[(size_t)(8 * g + 4) * SPAT], v5 = xp[(size_t)(8 * g + 5) * SPAT];
    float v6 = xp[(size_t)(8 * g + 6) * SPAT], v7 = xp[(size_t)(8 * g + 7) * SPAT];
    uint4 st;
    st.x = pack2((v0 - mu) * rs * lw[8*g+0] + lb[8*g+0], (v1 - mu) * rs * lw[8*g+1] + lb[8*g+1]);
    st.y = pack2((v2 - mu) * rs * lw[8*g+2] + lb[8*g+2], (v3 - mu) * rs * lw[8*g+3] + lb[8*g+3]);
    st.z = pack2((v4 - mu) * rs * lw[8*g+4] + lb[8*g+4], (v5 - mu) * rs * lw[8*g+5] + lb[8*g+5]);
    st.w = pack2((v6 - mu) * rs * lw[8*g+6] + lb[8*g+6], (v7 - mu) * rs * lw[8*g+7] + lb[8*g+7]);
    *reinterpret_cast<uint4*>(op + g * 8) = st;
  }
}

// ---------- kernel 6: FFN implicit GEMM via MFMA (channel-last xpad) ----------
// 784 blocks = 2 co-halves x 392 sp-tiles; 8 waves x 512 thr.
// wls row stride 108 u16 (54 dwords == 22 mod 32): 16 lanes hit 16 distinct banks.
__global__ __launch_bounds__(512)
void k_ffn_mfma(const u16t* __restrict__ xpad, const u16t* __restrict__ wcomb,
                const float* __restrict__ bcomb, float* __restrict__ out) {
  __shared__ __align__(16) u16t wls[2][48 * 108];
  int tid = threadIdx.x;
  int lane = tid & 63, wv = tid >> 6;        // wv 0..7
  int c = lane & 15, kg = lane >> 4;
  int bid = blockIdx.x;
  int coh = bid & 1;                         // co half
  int sp = bid >> 1;                         // spatial tile 0..391
  int swz = (sp & 7) * 49 + (sp >> 3);       // bijective: 392 = 8*49
  int m = swz * 128 + wv * 16 + c;
  int b = m / SPAT, r = m % SPAT;
  int d = r / 3136, r2 = r % 3136, h = r2 / 56, w = r2 % 56;
  int psp0 = ((b * 10 + d) * 58 + h) * 58 + w;
  int pbase = psp0 * 96 + kg * 8;
  int obase = b * (96 * SPAT) + r;

  f32x4 acc[3];
  #pragma unroll
  for (int ff = 0; ff < 3; ++ff) acc[ff] = (f32x4){0.f, 0.f, 0.f, 0.f};

  {
    const uint4* src = (const uint4*)(wcomb) + coh * 576;
    for (int e = tid; e < 576; e += 512) {
      uint4 v = src[e];
      int lco = (e * 8) / 96, ci = (e * 8) % 96;
      *reinterpret_cast<uint4*>(&wls[0][lco * 108 + ci]) = v;
    }
  }
  __syncthreads();
  int buf = 0;
  for (int ko = 0; ko < 27; ++ko) {
    int kd = ko / 9, kh = (ko / 3) % 3, kw = ko % 3;
    int tapoff = (kd * PHW + kh * PW + kw) * 96;
    if (ko + 1 < 27) {
      const uint4* src = (const uint4*)(wcomb) + (ko + 1) * 1152 + coh * 576;
      for (int e = tid; e < 576; e += 512) {
        uint4 v = src[e];
        int lco = (e * 8) / 96, ci = (e * 8) % 96;
        *reinterpret_cast<uint4*>(&wls[buf ^ 1][lco * 108 + ci]) = v;
      }
    }
    #pragma unroll
    for (int cc = 0; cc < 3; ++cc) {
      short8 bv = *reinterpret_cast<const short8*>(xpad + pbase + tapoff + cc * 32);
      #pragma unroll
      for (int ff = 0; ff < 3; ++ff) {
        short8 av = *reinterpret_cast<const short8*>(
            &wls[buf][(ff * 16 + c) * 108 + cc * 32 + kg * 8]);
        acc[ff] = __builtin_amdgcn_mfma_f32_16x16x32_bf16(av, bv, acc[ff], 0, 0, 0);
      }
    }
    __syncthreads();
    buf ^= 1;
  }
  #pragma unroll
  for (int ff = 0; ff < 3; ++ff)
    #pragma unroll
    for (int j = 0; j < 4; ++j) {
      int co = coh * 48 + ff * 16 + kg * 4 + j;
      float* o = out + obase + co * SPAT;
      *o = *o + acc[ff][j] + bcomb[co];
    }
}

extern "C" void kernel_launch(void* const* d_in, const int* in_sizes, int n_in,
                              void* d_out, int out_size, void* d_ws, size_t ws_size,
                              hipStream_t stream) {
  (void)in_sizes; (void)n_in; (void)out_size; (void)ws_size;
  const float* x      = (const float*)d_in[0];
  const float* ln1w   = (const float*)d_in[1];
  const float* ln1b   = (const float*)d_in[2];
  const float* ln2w   = (const float*)d_in[3];
  const float* ln2b   = (const float*)d_in[4];
  const float* qkvw0  = (const float*)d_in[5];
  const float* qkvb0  = (const float*)d_in[6];
  const float* projw0 = (const float*)d_in[7];
  const float* projb0 = (const float*)d_in[8];
  const float* rpb0   = (const float*)d_in[9];
  const float* qkvw1  = (const float*)d_in[10];
  const float* qkvb1  = (const float*)d_in[11];
  const float* projw1 = (const float*)d_in[12];
  const float* projb1 = (const float*)d_in[13];
  const float* rpb1   = (const float*)d_in[14];
  const float* aattn  = (const float*)d_in[15];
  const float* c3w    = (const float*)d_in[16];
  const float* c3b    = (const float*)d_in[17];
  const float* c1w    = (const float*)d_in[18];
  const float* c1b    = (const float*)d_in[19];
  const float* dww    = (const float*)d_in[20];
  const float* dwb    = (const float*)d_in[21];
  const float* affn   = (const float*)d_in[22];

  // workspace (u16 units)
  u16t* u    = (u16t*)d_ws;
  u16t* xw   = u;                                  // 50176*96
  u16t* a0   = xw + (size_t)NTOKTOT * 96;          // 3*50176*32
  u16t* a1   = a0 + (size_t)3 * NTOKTOT * 32;      // 6*50176*16
  u16t* qkvh = a1 + (size_t)6 * NTOKTOT * 16;      // 3*50176*96 (q|k|v head-major)
  u16t* wq   = qkvh + (size_t)3 * NTOKTOT * 96;    // 2*27648
  u16t* rpbc0 = wq + 2 * 27648;                    // 3*2536
  u16t* rpbc1 = rpbc0 + 3 * 2536;                  // 6*2536
  u16t* xpad  = qkvh;                              // reuse (dead after attn), channel-last
  u16t* wcomb = xpad + XPAD_U16;
  float* bcomb = (float*)(wcomb + WCOMB_N);
  u16t* wproj = (u16t*)(bcomb + 96);
  float* bproj = (float*)(wproj + WPROJ_N);
  float* x1  = (float*)d_out;

  k_ln1_win<<<196, 256, 0, stream>>>(x, ln1w, ln1b, xw);
  k_qprep<<<216, 256, 0, stream>>>(qkvw0, qkvw1, wq);
  k_rprep<3><<<30, 256, 0, stream>>>(rpb0, rpbc0);
  k_rprep<6><<<60, 256, 0, stream>>>(rpb1, rpbc1);
  k_qkv_mfma<32><<<784, 256, 0, stream>>>(xw, wq, qkvb0, qkvh);
  k_attn_mfma<3, 32><<<768, 512, 0, stream>>>(qkvh, rpbc0, a0);
  k_qkv_mfma<16><<<784, 256, 0, stream>>>(xw, wq + 27648, qkvb1, qkvh);
  k_attn_mfma<6, 16><<<768, 512, 0, stream>>>(qkvh, rpbc1, a1);
  // qkvh dead: build xpad / combined weights in its place
  k_zero<<<(XPAD_U16 / 8 + 255) / 256, 256, 0, stream>>>((uint4*)xpad, XPAD_U16 / 8);
  k_wprep<<<(WCOMB_N + 255) / 256, 256, 0, stream>>>(c3w, c3b, c1w, c1b, dww, dwb,
                                                     affn, wcomb, bcomb);
  k_pprep<<<(WPROJ_N + 255) / 256, 256, 0, stream>>>(projw0, projb0, projw1, projb1,
                                                     aattn, wproj, bproj);
  k_proj_mfma<<<784, 256, 0, stream>>>(a0, a1, wproj, bproj, x, x1);
  k_ln2pad<<<196, 256, 0, stream>>>(x1, ln2w, ln2b, xpad);
  k_ffn_mfma<<<784, 512, 0, stream>>>(xpad, wcomb, bcomb, (float*)d_out);
}